// Round 6
// baseline (1269.296 us; speedup 1.0000x reference)
//
#include <hip/hip_runtime.h>
#include <hip/hip_bf16.h>
#include <cstdint>
#include <cstddef>

// ---- problem constants ----
#define B_   2
#define D_   8
#define C_   256
#define W_   84
#define H_   84
#define NH   8
#define HD   32
#define NTOK 98
#define WH   7056        // W_*H_
#define M2   56448       // rows per chunk = 576 windows * 98 (441 * 128)
#define NWC  576         // windows per chunk

typedef __attribute__((ext_vector_type(8))) short sh8;
typedef __attribute__((ext_vector_type(4))) float f32x4;
typedef __hip_bfloat16 bf16;

// ---------------- fp32 -> bf16 weight convert ----------------
__global__ __launch_bounds__(256) void k_f2b(const float* __restrict__ in,
                                             bf16* __restrict__ out, int n) {
  int i = blockIdx.x * 256 + threadIdx.x;
  if (i < n) out[i] = __float2bfloat16(in[i]);
}

// ---------------- bias+mask table: [8 cls][8 h][112][112] f32 ----------------
__global__ __launch_bounds__(256) void k_bias(const float* __restrict__ rpb,
                                              float* __restrict__ tbl) {
  int cls = blockIdx.x >> 3, h = blockIdx.x & 7;
  int dB = cls >> 2, hB = (cls >> 1) & 1, wB = cls & 1;
  for (int idx = threadIdx.x; idx < 112 * 112; idx += 256) {
    int r = idx / 112, c = idx - (idx / 112) * 112;
    int rt = r < 98 ? r : 97, ct = c < 98 ? c : 97;
    int jdr = rt / 49, remr = rt % 49, jhr = remr / 7, jwr = remr % 7;
    int jdc = ct / 49, remc = ct % 49, jhc = remc / 7, jwc = remc % 7;
    int bir = jdr * 169 + jhr * 13 + jwr, bic = jdc * 169 + jhc * 13 + jwc;
    int dgr = dB ? ((6 + jdr) < 7 ? 1 : 2) : 0;
    int hgr = hB ? ((77 + jhr) < 81 ? 1 : 2) : 0;
    int wgr = wB ? ((77 + jwr) < 81 ? 1 : 2) : 0;
    int dgc = dB ? ((6 + jdc) < 7 ? 1 : 2) : 0;
    int hgc = hB ? ((77 + jhc) < 81 ? 1 : 2) : 0;
    int wgc = wB ? ((77 + jwc) < 81 ? 1 : 2) : 0;
    int cir = dgr * 9 + hgr * 3 + wgr, cic = dgc * 9 + hgc * 3 + wgc;
    float v = rpb[(bir - bic + 253) * 8 + h] + (cir == cic ? 0.f : -100.f);
    tbl[((size_t)(cls * 8 + h) * 112 + r) * 112 + c] = v;
  }
}

// inverse map: src/dst plane (b,d0,w0,h0) -> chunk-local row
__device__ __forceinline__ int inv_row(int b, int d0, int w0, int h0) {
  int sd = (d0 + 7) & 7;
  int lid = (sd >> 1) & 1, jd = sd & 1;
  int sh = h0 + 81; if (sh >= 84) sh -= 84;
  int sw = w0 + 81; if (sw >= 84) sw -= 84;
  int ih = sh / 7, jh = sh - ih * 7;
  int iw = sw / 7, jw = sw - iw * 7;
  return (b * 288 + lid * 144 + ih * 12 + iw) * 98 + jd * 49 + jh * 7 + jw;
}

// ---------------- x (B,D,C,W,H) -> xtw windowed rows x 256, f32 ----------------
__global__ __launch_bounds__(256) void k_xpose_w(const float* __restrict__ x,
                                                 float* __restrict__ xtw, int cchunk) {
  int blk = blockIdx.x;            // 1344 = 2ch * 84w * 4i * 2b
  int ch = blk & 1;
  int t = blk >> 1;
  int w0 = t % 84;
  int t2 = t / 84;
  int i = t2 & 3, b = t2 >> 2;
  int d0 = (cchunk * 4 + 1 + i) & 7;
  __shared__ float tile[128][85];
  __shared__ int rtab[84];
  int tid = threadIdx.x;
  if (tid < 84) rtab[tid] = inv_row(b, d0, w0, tid);
  const float* src = x + ((size_t)(b * 8 + d0) * 256 + ch * 128) * WH + w0 * 84;
  for (int idx = tid; idx < 128 * 21; idx += 256) {
    int c = idx / 21, h4 = idx - c * 21;
    float4 v = *(const float4*)(src + (size_t)c * WH + h4 * 4);
    tile[c][h4 * 4 + 0] = v.x; tile[c][h4 * 4 + 1] = v.y;
    tile[c][h4 * 4 + 2] = v.z; tile[c][h4 * 4 + 3] = v.w;
  }
  __syncthreads();
  for (int idx = tid; idx < 84 * 128; idx += 256) {
    int h = idx >> 7, cc = idx & 127;
    xtw[(size_t)rtab[h] * 256 + ch * 128 + cc] = tile[cc][h];
  }
}

// ---------------- LN1: linear streaming ----------------
__global__ __launch_bounds__(256) void k_ln1_lin(
    const float* __restrict__ xtw, const float* __restrict__ g,
    const float* __restrict__ bb, bf16* __restrict__ xw) {
  int rl = blockIdx.x * 4 + (threadIdx.x >> 6);
  int lane = threadIdx.x & 63;
  int c0 = lane * 4;
  float4 v = *(const float4*)(xtw + (size_t)rl * 256 + c0);
  float s = v.x + v.y + v.z + v.w;
  float s2 = v.x * v.x + v.y * v.y + v.z * v.z + v.w * v.w;
#pragma unroll
  for (int off = 32; off; off >>= 1) { s += __shfl_xor(s, off, 64); s2 += __shfl_xor(s2, off, 64); }
  float mu = s * (1.f / 256.f);
  float var = s2 * (1.f / 256.f) - mu * mu;
  float rs = rsqrtf(var + 1e-5f);
  float4 gg = *(const float4*)(g + c0);
  float4 bv = *(const float4*)(bb + c0);
  bf16 tmp[4];
  tmp[0] = __float2bfloat16((v.x - mu) * rs * gg.x + bv.x);
  tmp[1] = __float2bfloat16((v.y - mu) * rs * gg.y + bv.y);
  tmp[2] = __float2bfloat16((v.z - mu) * rs * gg.z + bv.z);
  tmp[3] = __float2bfloat16((v.w - mu) * rs * gg.w + bv.w);
  *(ushort4*)(&xw[(size_t)rl * 256 + c0]) = *(ushort4*)tmp;
}

// fast exact-GELU: erf via Abramowitz-Stegun 7.1.26 (|err| ~ 3e-7)
__device__ __forceinline__ float gelu_fast(float v) {
  float x = v * 0.70710678118f;
  float ax = fabsf(x);
  float t = 1.0f / (1.0f + 0.3275911f * ax);
  float y = t * (0.254829592f + t * (-0.284496736f +
            t * (1.421413741f + t * (-1.453152027f + t * 1.061405429f))));
  float er = 1.0f - y * __expf(-ax * ax);
  er = copysignf(er, x);
  return 0.5f * v * (1.0f + er);
}

// ---------------- bf16 B^T GEMM with global_load_lds staging ----------------
// EPI 0: (+bias) -> bf16   EPI 1: +bias, GELU -> bf16   EPI 2: +bias +res -> f32 linear
// Epilogue staged through LDS for coalesced vector stores.
template <int EPI>
__global__ __launch_bounds__(256) void k_gemm_bt(
    const bf16* __restrict__ A, const bf16* __restrict__ Bw,
    int M, int N, int K,
    const float* __restrict__ bias, const float* __restrict__ res,
    void* __restrict__ outv) {
  __shared__ __align__(16) short smem[16896];   // 33792 B: sA|sB, reused for C-stage
  short* sA = smem;
  short* sB = smem + 8192;
  int nbn = N >> 7;
  int bm = blockIdx.x / nbn, bn = blockIdx.x - bm * nbn;
  int tid = threadIdx.x;
  int lane = tid & 63, wv = tid >> 6;
  int wr = wv >> 1, wc = wv & 1;
  f32x4 acc[4][4] = {};
  const short* Ag = (const short*)A + (size_t)bm * 128 * K;
  const short* Bg = (const short*)Bw + (size_t)bn * 128 * K;
  int rA = wv * 32 + (lane >> 3);
  int cA = (lane & 7) * 8;
  int nk = K >> 6;
  for (int kt = 0; kt < nk; ++kt) {
    const short* ga = Ag + (size_t)rA * K + kt * 64 + cA;
    const short* gb = Bg + (size_t)rA * K + kt * 64 + cA;
#pragma unroll
    for (int rr = 0; rr < 4; ++rr) {
      __builtin_amdgcn_global_load_lds(
          (const __attribute__((address_space(1))) void*)(ga + (size_t)rr * 8 * K),
          (__attribute__((address_space(3))) void*)&sA[(wv * 32 + rr * 8) * 64], 16, 0, 0);
      __builtin_amdgcn_global_load_lds(
          (const __attribute__((address_space(1))) void*)(gb + (size_t)rr * 8 * K),
          (__attribute__((address_space(3))) void*)&sB[(wv * 32 + rr * 8) * 64], 16, 0, 0);
    }
    __syncthreads();
#pragma unroll
    for (int ks = 0; ks < 2; ++ks) {
      sh8 af[4], bfr[4];
      int rb = wr * 64 + (lane & 15);
      int cb = wc * 64 + (lane & 15);
      int kof = ks * 32 + (lane >> 4) * 8;
#pragma unroll
      for (int m = 0; m < 4; ++m) af[m] = *(const sh8*)&sA[(rb + m * 16) * 64 + kof];
#pragma unroll
      for (int n2 = 0; n2 < 4; ++n2) bfr[n2] = *(const sh8*)&sB[(cb + n2 * 16) * 64 + kof];
#pragma unroll
      for (int m = 0; m < 4; ++m)
#pragma unroll
        for (int n2 = 0; n2 < 4; ++n2)
          acc[m][n2] = __builtin_amdgcn_mfma_f32_16x16x32_bf16(af[m], bfr[n2], acc[m][n2], 0, 0, 0);
    }
    __syncthreads();
  }
  // ---- epilogue: LDS-stage C tile (two 64-row halves), coalesced stores ----
  int lrb = (lane >> 4) << 2;          // 0,4,8,12
  int lcb = wc * 64 + (lane & 15);
  int gcol0 = bn * 128;
  if (EPI == 2) {
    float* cs = (float*)smem;          // [64][132] f32 = 33792 B
    for (int half = 0; half < 2; ++half) {
      __syncthreads();
      if (wr == half) {
#pragma unroll
        for (int m = 0; m < 4; ++m)
#pragma unroll
          for (int j = 0; j < 4; ++j)
#pragma unroll
            for (int n2 = 0; n2 < 4; ++n2) {
              int cc = lcb + n2 * 16;
              cs[(m * 16 + lrb + j) * 132 + cc] = acc[m][n2][j] + bias[gcol0 + cc];
            }
      }
      __syncthreads();
      int rr = tid >> 2, qc = (tid & 3) * 32;
      int gr = bm * 128 + half * 64 + rr;
      const float* rp = res + (size_t)gr * N + gcol0 + qc;
      float* op = (float*)outv + (size_t)gr * N + gcol0 + qc;
#pragma unroll
      for (int q = 0; q < 8; ++q) {
        float4 cv = *(float4*)&cs[rr * 132 + qc + q * 4];
        float4 rv = *(const float4*)&rp[q * 4];
        cv.x += rv.x; cv.y += rv.y; cv.z += rv.z; cv.w += rv.w;
        *(float4*)&op[q * 4] = cv;
      }
    }
  } else {
    short* cs = smem;                  // [64][136] bf16 = 17408 B
    for (int half = 0; half < 2; ++half) {
      __syncthreads();
      if (wr == half) {
#pragma unroll
        for (int m = 0; m < 4; ++m)
#pragma unroll
          for (int j = 0; j < 4; ++j)
#pragma unroll
            for (int n2 = 0; n2 < 4; ++n2) {
              int cc = lcb + n2 * 16;
              float v = acc[m][n2][j];
              if (bias) v += bias[gcol0 + cc];
              if (EPI == 1) v = gelu_fast(v);
              bf16 bv = __float2bfloat16(v);
              cs[(m * 16 + lrb + j) * 136 + cc] = *(short*)&bv;
            }
      }
      __syncthreads();
      int rr = tid >> 2, qc = (tid & 3) * 32;
      int gr = bm * 128 + half * 64 + rr;
      bf16* op = (bf16*)outv + (size_t)gr * N + gcol0 + qc;
#pragma unroll
      for (int q = 0; q < 4; ++q) {
        sh8 cv = *(sh8*)&cs[rr * 136 + qc + q * 8];
        *(sh8*)&op[q * 8] = cv;
      }
    }
  }
}

// ---------------- MFMA windowed attention: 1 wave per (window, head) ----------------
__global__ __launch_bounds__(64) void k_attn_mfma(
    const bf16* __restrict__ qkv, const float* __restrict__ tbl,
    bf16* __restrict__ aout, int idbase) {
  int blk = blockIdx.x;
  int wl = blk >> 3, h = blk & 7;
  int lid = (wl / 144) & 1;
  int id = idbase + lid;
  int rem = wl % 144;
  int ih = rem / 12, iw = rem - ih * 12;
  int cls = ((id == 3) ? 4 : 0) + ((ih == 11) ? 2 : 0) + ((iw == 11) ? 1 : 0);
  const float* bt = tbl + (size_t)(cls * 8 + h) * 112 * 112;
  int lane = threadIdx.x;
  __shared__ __align__(16) short vt[32][136];   // V^T, padded
  __shared__ __align__(16) short pb[16][136];   // P band
  sh8 z = {};
  for (int i = lane; i < 544; i += 64) *((sh8*)&vt[0][0] + i) = z;
  for (int i = lane; i < 272; i += 64) *((sh8*)&pb[0][0] + i) = z;
  __syncthreads();
  const size_t base = (size_t)wl * NTOK * 768;
  for (int i = lane; i < 98 * 8; i += 64) {
    int c = i >> 3, d4 = (i & 7) * 4;
    ushort4 vu = *(const ushort4*)&qkv[base + (size_t)c * 768 + 512 + h * 32 + d4];
    vt[d4 + 0][c] = (short)vu.x; vt[d4 + 1][c] = (short)vu.y;
    vt[d4 + 2][c] = (short)vu.z; vt[d4 + 3][c] = (short)vu.w;
  }
  int kq = (lane >> 4) * 8;
  sh8 kf[7];
#pragma unroll
  for (int jt = 0; jt < 7; ++jt) {
    int c = jt * 16 + (lane & 15);
    kf[jt] = *(const sh8*)&qkv[base + (size_t)c * 768 + 256 + h * 32 + kq];
  }
  __syncthreads();
  sh8 vb[2][4];
#pragma unroll
  for (int dt = 0; dt < 2; ++dt)
#pragma unroll
    for (int k2 = 0; k2 < 4; ++k2)
      vb[dt][k2] = *(const sh8*)&vt[dt * 16 + (lane & 15)][k2 * 32 + kq];

  const float scale = 0.17677669529663687f;
  f32x4 zc = {};
  int rband = (lane >> 4) * 4;
  for (int it = 0; it < 7; ++it) {
    int rq = it * 16 + (lane & 15);
    sh8 qf = *(const sh8*)&qkv[base + (size_t)rq * 768 + h * 32 + kq];
    f32x4 s[7];
#pragma unroll
    for (int jt = 0; jt < 7; ++jt)
      s[jt] = __builtin_amdgcn_mfma_f32_16x16x32_bf16(qf, kf[jt], zc, 0, 0, 0);
    float p[7][4], linv[4];
#pragma unroll
    for (int j = 0; j < 4; ++j) {
      int r2 = it * 16 + rband + j;
      float rs = 0.f;
#pragma unroll
      for (int jt = 0; jt < 7; ++jt) {
        int c = jt * 16 + (lane & 15);
        float v = s[jt][j] * scale + bt[r2 * 112 + c];
        float e = __expf(v);
        if (jt == 6 && (lane & 15) >= 2) e = 0.f;
        p[jt][j] = e;
        rs += e;
      }
      rs += __shfl_xor(rs, 1, 64); rs += __shfl_xor(rs, 2, 64);
      rs += __shfl_xor(rs, 4, 64); rs += __shfl_xor(rs, 8, 64);
      linv[j] = 1.f / rs;
    }
#pragma unroll
    for (int j = 0; j < 4; ++j)
#pragma unroll
      for (int jt = 0; jt < 7; ++jt) {
        bf16 bv = __float2bfloat16(p[jt][j] * linv[j]);
        pb[rband + j][jt * 16 + (lane & 15)] = *(short*)&bv;
      }
    __syncthreads();
    sh8 pa[4];
#pragma unroll
    for (int k2 = 0; k2 < 4; ++k2)
      pa[k2] = *(const sh8*)&pb[lane & 15][k2 * 32 + kq];
    f32x4 o[2] = {};
#pragma unroll
    for (int dt = 0; dt < 2; ++dt)
#pragma unroll
      for (int k2 = 0; k2 < 4; ++k2)
        o[dt] = __builtin_amdgcn_mfma_f32_16x16x32_bf16(pa[k2], vb[dt][k2], o[dt], 0, 0, 0);
#pragma unroll
    for (int j = 0; j < 4; ++j) {
      int r2 = it * 16 + rband + j;
      if (r2 < 98) {
#pragma unroll
        for (int dt = 0; dt < 2; ++dt) {
          bf16 ov = __float2bfloat16(o[dt][j]);
          aout[((size_t)wl * 98 + r2) * 256 + h * 32 + dt * 16 + (lane & 15)] = ov;
        }
      }
    }
    __syncthreads();
  }
}

// ---------------- residual + LN2: linear streaming ----------------
__global__ __launch_bounds__(256) void k_xres_ln2_lin(
    const float* __restrict__ xtw, const bf16* __restrict__ pout,
    const float* __restrict__ g, const float* __restrict__ bb,
    float* __restrict__ xres, bf16* __restrict__ ln2) {
  int rl = blockIdx.x * 4 + (threadIdx.x >> 6);
  int lane = threadIdx.x & 63;
  int c0 = lane * 4;
  float4 v = *(const float4*)(xtw + (size_t)rl * 256 + c0);
  ushort4 pu = *(const ushort4*)(pout + (size_t)rl * 256 + c0);
  v.x += __bfloat162float(*(bf16*)&pu.x);
  v.y += __bfloat162float(*(bf16*)&pu.y);
  v.z += __bfloat162float(*(bf16*)&pu.z);
  v.w += __bfloat162float(*(bf16*)&pu.w);
  *(float4*)(xres + (size_t)rl * 256 + c0) = v;
  float s = v.x + v.y + v.z + v.w;
  float s2 = v.x * v.x + v.y * v.y + v.z * v.z + v.w * v.w;
#pragma unroll
  for (int off = 32; off; off >>= 1) { s += __shfl_xor(s, off, 64); s2 += __shfl_xor(s2, off, 64); }
  float mu = s * (1.f / 256.f);
  float var = s2 * (1.f / 256.f) - mu * mu;
  float rs = rsqrtf(var + 1e-5f);
  float4 gg = *(const float4*)(g + c0);
  float4 bv = *(const float4*)(bb + c0);
  bf16 tmp[4];
  tmp[0] = __float2bfloat16((v.x - mu) * rs * gg.x + bv.x);
  tmp[1] = __float2bfloat16((v.y - mu) * rs * gg.y + bv.y);
  tmp[2] = __float2bfloat16((v.z - mu) * rs * gg.z + bv.z);
  tmp[3] = __float2bfloat16((v.w - mu) * rs * gg.w + bv.w);
  *(ushort4*)(&ln2[(size_t)rl * 256 + c0]) = *(ushort4*)tmp;
}

// ---------------- final: chunk-local y (f32 windowed) -> (B,D,C,W,H) ----------------
__global__ __launch_bounds__(256) void k_final_c(const float* __restrict__ y,
                                                 float* __restrict__ out, int cchunk) {
  int t = blockIdx.x;              // 672 = 84w * 4i * 2b
  int w0 = t % 84;
  int t2 = t / 84;
  int i = t2 & 3, b = t2 >> 2;
  int d0 = (cchunk * 4 + 1 + i) & 7;
  __shared__ float tile[84][65];
  __shared__ int rtab[84];
  int tid = threadIdx.x;
  if (tid < 84) rtab[tid] = inv_row(b, d0, w0, tid);
  __syncthreads();
  for (int c0 = 0; c0 < 256; c0 += 64) {
    for (int idx = tid; idx < 84 * 64; idx += 256) {
      int hh = idx >> 6, cc = idx & 63;
      tile[hh][cc] = y[(size_t)rtab[hh] * 256 + c0 + cc];
    }
    __syncthreads();
    for (int idx = tid; idx < 64 * 84; idx += 256) {
      int cc = idx / 84, hh = idx - cc * 84;
      out[((((size_t)b * 8 + d0) * 256 + c0 + cc) * 84 + w0) * 84 + hh] = tile[hh][cc];
    }
    __syncthreads();
  }
}

// ---------------- launch ----------------
extern "C" void kernel_launch(void* const* d_in, const int* in_sizes, int n_in,
                              void* d_out, int out_size, void* d_ws, size_t ws_size,
                              hipStream_t stream) {
  const float* x      = (const float*)d_in[0];
  const float* n1g    = (const float*)d_in[1];
  const float* n1b    = (const float*)d_in[2];
  const float* qkv_w  = (const float*)d_in[3];
  const float* rpb    = (const float*)d_in[4];
  const float* proj_w = (const float*)d_in[5];
  const float* proj_b = (const float*)d_in[6];
  const float* n2g    = (const float*)d_in[7];
  const float* n2b    = (const float*)d_in[8];
  const float* fc1_w  = (const float*)d_in[9];
  const float* fc1_b  = (const float*)d_in[10];
  const float* fc2_w  = (const float*)d_in[11];
  const float* fc2_b  = (const float*)d_in[12];
  float* out = (float*)d_out;

  // ---- persistent: weights + bias table ----
  char* w = (char*)d_ws;
  size_t off = 0;
  bf16* wq = (bf16*)(w + off); off += (size_t)768 * 256 * 2;
  bf16* wp = (bf16*)(w + off); off += (size_t)256 * 256 * 2;
  bf16* w1 = (bf16*)(w + off); off += (size_t)1024 * 256 * 2;
  bf16* w2 = (bf16*)(w + off); off += (size_t)1024 * 256 * 2;
  float* tbl = (float*)(w + off); off += (size_t)8 * 8 * 112 * 112 * 4;  // 3.2 MB

  // ---- per-chunk buffers (~274 MB total; known-good budget ~290 MB) ----
  float* xtw  = (float*)(w + off); off += (size_t)M2 * 1024;    // 57.8 MB (also y)
  bf16*  xw   = (bf16*)(w + off);  off += (size_t)M2 * 512;     // 28.9 MB (also aout)
  char*  qreg = w + off;           off += (size_t)M2 * 1536;    // 86.7 MB
  float* xres = (float*)(w + off); off += (size_t)M2 * 1024;    // 57.8 MB
  bf16*  hid  = (bf16*)(w + off);                               // sub-chunk sized
  bf16* qkvb = (bf16*)qreg;
  bf16* aout = xw;
  bf16* pout = (bf16*)qreg;
  bf16* ln2b = (bf16*)(qreg + (size_t)M2 * 512);
  float* ybuf = xtw;

  // MLP sub-chunk tiers: 147/49/21 row-tiles
  int subTiles = 21;
  if (off + (size_t)147 * 128 * 2048 + 1024 <= ws_size) subTiles = 147;
  else if (off + (size_t)49 * 128 * 2048 + 1024 <= ws_size) subTiles = 49;
  const int nsub = 441 / subTiles;
  const int MSUB = subTiles * 128;

  // weights -> bf16, bias table
  k_f2b<<<(196608 + 255) / 256, 256, 0, stream>>>(qkv_w, wq, 196608);
  k_f2b<<<(65536 + 255) / 256, 256, 0, stream>>>(proj_w, wp, 65536);
  k_f2b<<<(262144 + 255) / 256, 256, 0, stream>>>(fc1_w, w1, 262144);
  k_f2b<<<(262144 + 255) / 256, 256, 0, stream>>>(fc2_w, w2, 262144);
  k_bias<<<64, 256, 0, stream>>>(rpb, tbl);

  for (int c = 0; c < 2; ++c) {
    k_xpose_w<<<1344, 256, 0, stream>>>(x, xtw, c);
    k_ln1_lin<<<M2 / 4, 256, 0, stream>>>(xtw, n1g, n1b, xw);
    k_gemm_bt<0><<<441 * 6, 256, 0, stream>>>(xw, wq, M2, 768, 256, nullptr, nullptr, qkvb);
    k_attn_mfma<<<NWC * NH, 64, 0, stream>>>(qkvb, tbl, aout, 2 * c);
    k_gemm_bt<0><<<441 * 2, 256, 0, stream>>>(aout, wp, M2, 256, 256, proj_b, nullptr, pout);
    k_xres_ln2_lin<<<M2 / 4, 256, 0, stream>>>(xtw, pout, n2g, n2b, xres, ln2b);
    for (int s = 0; s < nsub; ++s) {
      size_t m0 = (size_t)s * MSUB;
      k_gemm_bt<1><<<subTiles * 8, 256, 0, stream>>>(
          ln2b + m0 * 256, w1, MSUB, 1024, 256, fc1_b, nullptr, hid);
      k_gemm_bt<2><<<subTiles * 2, 256, 0, stream>>>(
          hid, w2, MSUB, 256, 1024, fc2_b, xres + m0 * 256, ybuf + m0 * 256);
    }
    k_final_c<<<672, 256, 0, stream>>>(ybuf, out, c);
  }
}

// Round 7
// 1010.297 us; speedup vs baseline: 1.2564x; 1.2564x over previous
//
#include <hip/hip_runtime.h>
#include <hip/hip_bf16.h>
#include <cstdint>
#include <cstddef>

// ---- problem constants ----
#define B_   2
#define D_   8
#define C_   256
#define W_   84
#define H_   84
#define NH   8
#define HD   32
#define NTOK 98
#define WH   7056        // W_*H_
#define M2   56448       // rows per chunk = 576 windows * 98 (441 * 128)
#define NWC  576         // windows per chunk

typedef __attribute__((ext_vector_type(8))) short sh8;
typedef __attribute__((ext_vector_type(4))) float f32x4;
typedef __hip_bfloat16 bf16;

// ---------------- fp32 -> bf16 weight convert ----------------
__global__ __launch_bounds__(256) void k_f2b(const float* __restrict__ in,
                                             bf16* __restrict__ out, int n) {
  int i = blockIdx.x * 256 + threadIdx.x;
  if (i < n) out[i] = __float2bfloat16(in[i]);
}

// ---------------- bias+mask table: [8 cls][8 h][112][112] f32 ----------------
__global__ __launch_bounds__(256) void k_bias(const float* __restrict__ rpb,
                                              float* __restrict__ tbl) {
  int cls = blockIdx.x >> 3, h = blockIdx.x & 7;
  int dB = cls >> 2, hB = (cls >> 1) & 1, wB = cls & 1;
  for (int idx = threadIdx.x; idx < 112 * 112; idx += 256) {
    int r = idx / 112, c = idx - (idx / 112) * 112;
    int rt = r < 98 ? r : 97, ct = c < 98 ? c : 97;
    int jdr = rt / 49, remr = rt % 49, jhr = remr / 7, jwr = remr % 7;
    int jdc = ct / 49, remc = ct % 49, jhc = remc / 7, jwc = remc % 7;
    int bir = jdr * 169 + jhr * 13 + jwr, bic = jdc * 169 + jhc * 13 + jwc;
    int dgr = dB ? ((6 + jdr) < 7 ? 1 : 2) : 0;
    int hgr = hB ? ((77 + jhr) < 81 ? 1 : 2) : 0;
    int wgr = wB ? ((77 + jwr) < 81 ? 1 : 2) : 0;
    int dgc = dB ? ((6 + jdc) < 7 ? 1 : 2) : 0;
    int hgc = hB ? ((77 + jhc) < 81 ? 1 : 2) : 0;
    int wgc = wB ? ((77 + jwc) < 81 ? 1 : 2) : 0;
    int cir = dgr * 9 + hgr * 3 + wgr, cic = dgc * 9 + hgc * 3 + wgc;
    float v = rpb[(bir - bic + 253) * 8 + h] + (cir == cic ? 0.f : -100.f);
    tbl[((size_t)(cls * 8 + h) * 112 + r) * 112 + c] = v;
  }
}

// inverse map: src/dst plane (b,d0,w0,h0) -> chunk-local row
__device__ __forceinline__ int inv_row(int b, int d0, int w0, int h0) {
  int sd = (d0 + 7) & 7;
  int lid = (sd >> 1) & 1, jd = sd & 1;
  int sh = h0 + 81; if (sh >= 84) sh -= 84;
  int sw = w0 + 81; if (sw >= 84) sw -= 84;
  int ih = sh / 7, jh = sh - ih * 7;
  int iw = sw / 7, jw = sw - iw * 7;
  return (b * 288 + lid * 144 + ih * 12 + iw) * 98 + jd * 49 + jh * 7 + jw;
}

// ---------------- x (B,D,C,W,H) -> xtw windowed rows x 256, f32 ----------------
__global__ __launch_bounds__(256) void k_xpose_w(const float* __restrict__ x,
                                                 float* __restrict__ xtw, int cchunk) {
  int blk = blockIdx.x;            // 1344 = 2ch * 84w * 4i * 2b
  int ch = blk & 1;
  int t = blk >> 1;
  int w0 = t % 84;
  int t2 = t / 84;
  int i = t2 & 3, b = t2 >> 2;
  int d0 = (cchunk * 4 + 1 + i) & 7;
  __shared__ float tile[128][85];
  __shared__ int rtab[84];
  int tid = threadIdx.x;
  if (tid < 84) rtab[tid] = inv_row(b, d0, w0, tid);
  const float* src = x + ((size_t)(b * 8 + d0) * 256 + ch * 128) * WH + w0 * 84;
  for (int idx = tid; idx < 128 * 21; idx += 256) {
    int c = idx / 21, h4 = idx - c * 21;
    float4 v = *(const float4*)(src + (size_t)c * WH + h4 * 4);
    tile[c][h4 * 4 + 0] = v.x; tile[c][h4 * 4 + 1] = v.y;
    tile[c][h4 * 4 + 2] = v.z; tile[c][h4 * 4 + 3] = v.w;
  }
  __syncthreads();
  for (int idx = tid; idx < 84 * 128; idx += 256) {
    int h = idx >> 7, cc = idx & 127;
    xtw[(size_t)rtab[h] * 256 + ch * 128 + cc] = tile[cc][h];
  }
}

// ---------------- LN1: linear streaming ----------------
__global__ __launch_bounds__(256) void k_ln1_lin(
    const float* __restrict__ xtw, const float* __restrict__ g,
    const float* __restrict__ bb, bf16* __restrict__ xw) {
  int rl = blockIdx.x * 4 + (threadIdx.x >> 6);
  int lane = threadIdx.x & 63;
  int c0 = lane * 4;
  float4 v = *(const float4*)(xtw + (size_t)rl * 256 + c0);
  float s = v.x + v.y + v.z + v.w;
  float s2 = v.x * v.x + v.y * v.y + v.z * v.z + v.w * v.w;
#pragma unroll
  for (int off = 32; off; off >>= 1) { s += __shfl_xor(s, off, 64); s2 += __shfl_xor(s2, off, 64); }
  float mu = s * (1.f / 256.f);
  float var = s2 * (1.f / 256.f) - mu * mu;
  float rs = rsqrtf(var + 1e-5f);
  float4 gg = *(const float4*)(g + c0);
  float4 bv = *(const float4*)(bb + c0);
  bf16 tmp[4];
  tmp[0] = __float2bfloat16((v.x - mu) * rs * gg.x + bv.x);
  tmp[1] = __float2bfloat16((v.y - mu) * rs * gg.y + bv.y);
  tmp[2] = __float2bfloat16((v.z - mu) * rs * gg.z + bv.z);
  tmp[3] = __float2bfloat16((v.w - mu) * rs * gg.w + bv.w);
  *(ushort4*)(&xw[(size_t)rl * 256 + c0]) = *(ushort4*)tmp;
}

// fast exact-GELU: erf via Abramowitz-Stegun 7.1.26 (|err| ~ 3e-7)
__device__ __forceinline__ float gelu_fast(float v) {
  float x = v * 0.70710678118f;
  float ax = fabsf(x);
  float t = 1.0f / (1.0f + 0.3275911f * ax);
  float y = t * (0.254829592f + t * (-0.284496736f +
            t * (1.421413741f + t * (-1.453152027f + t * 1.061405429f))));
  float er = 1.0f - y * __expf(-ax * ax);
  er = copysignf(er, x);
  return 0.5f * v * (1.0f + er);
}

// ---------------- bf16 B^T GEMM: double-buffered global_load_lds pipeline ----------------
// LDS layout: linear [row][64] shorts, content XOR-swizzled (chunk ^= row&7) via
// pre-swizzled global SOURCE address (gload_lds dest must stay linear, m104/m173);
// ds_read applies the same XOR -> conflict-free.
// EPI 0: (+bias) -> bf16   EPI 1: +bias, GELU -> bf16   EPI 2: +bias +res -> f32 linear
template <int EPI>
__global__ __launch_bounds__(256) void k_gemm_bt(
    const bf16* __restrict__ A, const bf16* __restrict__ Bw,
    int M, int N, int K,
    const float* __restrict__ bias, const float* __restrict__ res,
    void* __restrict__ outv) {
  __shared__ __align__(16) short smem[32768];   // 64 KB: 2 bufs x (sA 8192 | sB 8192)
  int nbn = N >> 7;
  int bm = blockIdx.x / nbn, bn = blockIdx.x - bm * nbn;
  int tid = threadIdx.x;
  int lane = tid & 63, wv = tid >> 6;
  int wr = wv >> 1, wc = wv & 1;
  f32x4 acc[4][4] = {};
  const short* Ag = (const short*)A + (size_t)bm * 128 * K;
  const short* Bg = (const short*)Bw + (size_t)bn * 128 * K;
  // staging: wave wv covers rows wv*32..+31; lane l -> row +(l>>3), dest chunk l&7.
  // source chunk = (l&7) ^ (row&7) = (l&7) ^ ((l>>3)&7)
  int rA = wv * 32 + (lane >> 3);
  int cSrc = ((lane & 7) ^ ((lane >> 3) & 7)) * 8;   // shorts
  int nk = K >> 6;

  auto stage = [&](int buf, int kt) {
    short* sA = smem + buf * 16384;
    short* sB = sA + 8192;
    const short* ga = Ag + (size_t)rA * K + kt * 64 + cSrc;
    const short* gb = Bg + (size_t)rA * K + kt * 64 + cSrc;
#pragma unroll
    for (int rr = 0; rr < 4; ++rr) {
      __builtin_amdgcn_global_load_lds(
          (const __attribute__((address_space(1))) void*)(ga + (size_t)rr * 8 * K),
          (__attribute__((address_space(3))) void*)&sA[(wv * 32 + rr * 8) * 64], 16, 0, 0);
      __builtin_amdgcn_global_load_lds(
          (const __attribute__((address_space(1))) void*)(gb + (size_t)rr * 8 * K),
          (__attribute__((address_space(3))) void*)&sB[(wv * 32 + rr * 8) * 64], 16, 0, 0);
    }
  };

  stage(0, 0);
  __syncthreads();
  int cur = 0;
  for (int kt = 0; kt < nk; ++kt) {
    if (kt + 1 < nk) stage(cur ^ 1, kt + 1);   // issue prefetch BEFORE compute
    const short* sA = smem + cur * 16384;
    const short* sB = sA + 8192;
#pragma unroll
    for (int ks = 0; ks < 2; ++ks) {
      sh8 af[4], bfr[4];
      int rb = wr * 64 + (lane & 15);
      int cb = wc * 64 + (lane & 15);
      int kswz = ((ks * 4 + (lane >> 4)) ^ (lane & 7)) * 8;   // swizzled 16B chunk
#pragma unroll
      for (int m = 0; m < 4; ++m) af[m] = *(const sh8*)&sA[(rb + m * 16) * 64 + kswz];
#pragma unroll
      for (int n2 = 0; n2 < 4; ++n2) bfr[n2] = *(const sh8*)&sB[(cb + n2 * 16) * 64 + kswz];
#pragma unroll
      for (int m = 0; m < 4; ++m)
#pragma unroll
        for (int n2 = 0; n2 < 4; ++n2)
          acc[m][n2] = __builtin_amdgcn_mfma_f32_16x16x32_bf16(af[m], bfr[n2], acc[m][n2], 0, 0, 0);
    }
    if (kt + 1 < nk) __syncthreads();          // single barrier per K-step
    cur ^= 1;
  }
  // direct epilogue (R5-measured-best style)
  int rbase = bm * 128 + wr * 64 + ((lane >> 4) << 2);
  int cbase = bn * 128 + wc * 64 + (lane & 15);
#pragma unroll
  for (int m = 0; m < 4; ++m) {
#pragma unroll
    for (int j = 0; j < 4; ++j) {
      int r = rbase + m * 16 + j;
#pragma unroll
      for (int n2 = 0; n2 < 4; ++n2) {
        int cc = cbase + n2 * 16;
        float v = acc[m][n2][j];
        if (EPI == 2) {
          v += bias[cc] + res[(size_t)r * N + cc];
          ((float*)outv)[(size_t)r * N + cc] = v;
        } else {
          if (bias) v += bias[cc];
          if (EPI == 1) v = gelu_fast(v);
          ((bf16*)outv)[(size_t)r * N + cc] = __float2bfloat16(v);
        }
      }
    }
  }
}

// ---------------- MFMA windowed attention: 1 wave per (window, head) ----------------
__global__ __launch_bounds__(64) void k_attn_mfma(
    const bf16* __restrict__ qkv, const float* __restrict__ tbl,
    bf16* __restrict__ aout, int idbase) {
  int blk = blockIdx.x;
  int wl = blk >> 3, h = blk & 7;
  int lid = (wl / 144) & 1;
  int id = idbase + lid;
  int rem = wl % 144;
  int ih = rem / 12, iw = rem - ih * 12;
  int cls = ((id == 3) ? 4 : 0) + ((ih == 11) ? 2 : 0) + ((iw == 11) ? 1 : 0);
  const float* bt = tbl + (size_t)(cls * 8 + h) * 112 * 112;
  int lane = threadIdx.x;
  __shared__ __align__(16) short vt[32][136];   // V^T, padded
  __shared__ __align__(16) short pb[16][136];   // P band
  sh8 z = {};
  for (int i = lane; i < 544; i += 64) *((sh8*)&vt[0][0] + i) = z;
  for (int i = lane; i < 272; i += 64) *((sh8*)&pb[0][0] + i) = z;
  __syncthreads();
  const size_t base = (size_t)wl * NTOK * 768;
  for (int i = lane; i < 98 * 8; i += 64) {
    int c = i >> 3, d4 = (i & 7) * 4;
    ushort4 vu = *(const ushort4*)&qkv[base + (size_t)c * 768 + 512 + h * 32 + d4];
    vt[d4 + 0][c] = (short)vu.x; vt[d4 + 1][c] = (short)vu.y;
    vt[d4 + 2][c] = (short)vu.z; vt[d4 + 3][c] = (short)vu.w;
  }
  int kq = (lane >> 4) * 8;
  sh8 kf[7];
#pragma unroll
  for (int jt = 0; jt < 7; ++jt) {
    int c = jt * 16 + (lane & 15);
    kf[jt] = *(const sh8*)&qkv[base + (size_t)c * 768 + 256 + h * 32 + kq];
  }
  __syncthreads();
  sh8 vb[2][4];
#pragma unroll
  for (int dt = 0; dt < 2; ++dt)
#pragma unroll
    for (int k2 = 0; k2 < 4; ++k2)
      vb[dt][k2] = *(const sh8*)&vt[dt * 16 + (lane & 15)][k2 * 32 + kq];

  const float scale = 0.17677669529663687f;
  f32x4 zc = {};
  int rband = (lane >> 4) * 4;
  for (int it = 0; it < 7; ++it) {
    int rq = it * 16 + (lane & 15);
    sh8 qf = *(const sh8*)&qkv[base + (size_t)rq * 768 + h * 32 + kq];
    f32x4 s[7];
#pragma unroll
    for (int jt = 0; jt < 7; ++jt)
      s[jt] = __builtin_amdgcn_mfma_f32_16x16x32_bf16(qf, kf[jt], zc, 0, 0, 0);
    float p[7][4], linv[4];
#pragma unroll
    for (int j = 0; j < 4; ++j) {
      int r2 = it * 16 + rband + j;
      float rs = 0.f;
#pragma unroll
      for (int jt = 0; jt < 7; ++jt) {
        int c = jt * 16 + (lane & 15);
        float v = s[jt][j] * scale + bt[r2 * 112 + c];
        float e = __expf(v);
        if (jt == 6 && (lane & 15) >= 2) e = 0.f;
        p[jt][j] = e;
        rs += e;
      }
      rs += __shfl_xor(rs, 1, 64); rs += __shfl_xor(rs, 2, 64);
      rs += __shfl_xor(rs, 4, 64); rs += __shfl_xor(rs, 8, 64);
      linv[j] = 1.f / rs;
    }
#pragma unroll
    for (int j = 0; j < 4; ++j)
#pragma unroll
      for (int jt = 0; jt < 7; ++jt) {
        bf16 bv = __float2bfloat16(p[jt][j] * linv[j]);
        pb[rband + j][jt * 16 + (lane & 15)] = *(short*)&bv;
      }
    __syncthreads();
    sh8 pa[4];
#pragma unroll
    for (int k2 = 0; k2 < 4; ++k2)
      pa[k2] = *(const sh8*)&pb[lane & 15][k2 * 32 + kq];
    f32x4 o[2] = {};
#pragma unroll
    for (int dt = 0; dt < 2; ++dt)
#pragma unroll
      for (int k2 = 0; k2 < 4; ++k2)
        o[dt] = __builtin_amdgcn_mfma_f32_16x16x32_bf16(pa[k2], vb[dt][k2], o[dt], 0, 0, 0);
#pragma unroll
    for (int j = 0; j < 4; ++j) {
      int r2 = it * 16 + rband + j;
      if (r2 < 98) {
#pragma unroll
        for (int dt = 0; dt < 2; ++dt) {
          bf16 ov = __float2bfloat16(o[dt][j]);
          aout[((size_t)wl * 98 + r2) * 256 + h * 32 + dt * 16 + (lane & 15)] = ov;
        }
      }
    }
    __syncthreads();
  }
}

// ---------------- residual + LN2: linear streaming ----------------
__global__ __launch_bounds__(256) void k_xres_ln2_lin(
    const float* __restrict__ xtw, const bf16* __restrict__ pout,
    const float* __restrict__ g, const float* __restrict__ bb,
    float* __restrict__ xres, bf16* __restrict__ ln2) {
  int rl = blockIdx.x * 4 + (threadIdx.x >> 6);
  int lane = threadIdx.x & 63;
  int c0 = lane * 4;
  float4 v = *(const float4*)(xtw + (size_t)rl * 256 + c0);
  ushort4 pu = *(const ushort4*)(pout + (size_t)rl * 256 + c0);
  v.x += __bfloat162float(*(bf16*)&pu.x);
  v.y += __bfloat162float(*(bf16*)&pu.y);
  v.z += __bfloat162float(*(bf16*)&pu.z);
  v.w += __bfloat162float(*(bf16*)&pu.w);
  *(float4*)(xres + (size_t)rl * 256 + c0) = v;
  float s = v.x + v.y + v.z + v.w;
  float s2 = v.x * v.x + v.y * v.y + v.z * v.z + v.w * v.w;
#pragma unroll
  for (int off = 32; off; off >>= 1) { s += __shfl_xor(s, off, 64); s2 += __shfl_xor(s2, off, 64); }
  float mu = s * (1.f / 256.f);
  float var = s2 * (1.f / 256.f) - mu * mu;
  float rs = rsqrtf(var + 1e-5f);
  float4 gg = *(const float4*)(g + c0);
  float4 bv = *(const float4*)(bb + c0);
  bf16 tmp[4];
  tmp[0] = __float2bfloat16((v.x - mu) * rs * gg.x + bv.x);
  tmp[1] = __float2bfloat16((v.y - mu) * rs * gg.y + bv.y);
  tmp[2] = __float2bfloat16((v.z - mu) * rs * gg.z + bv.z);
  tmp[3] = __float2bfloat16((v.w - mu) * rs * gg.w + bv.w);
  *(ushort4*)(&ln2[(size_t)rl * 256 + c0]) = *(ushort4*)tmp;
}

// ---------------- final: chunk-local y (f32 windowed) -> (B,D,C,W,H) ----------------
__global__ __launch_bounds__(256) void k_final_c(const float* __restrict__ y,
                                                 float* __restrict__ out, int cchunk) {
  int t = blockIdx.x;              // 672 = 84w * 4i * 2b
  int w0 = t % 84;
  int t2 = t / 84;
  int i = t2 & 3, b = t2 >> 2;
  int d0 = (cchunk * 4 + 1 + i) & 7;
  __shared__ float tile[84][65];
  __shared__ int rtab[84];
  int tid = threadIdx.x;
  if (tid < 84) rtab[tid] = inv_row(b, d0, w0, tid);
  __syncthreads();
  for (int c0 = 0; c0 < 256; c0 += 64) {
    for (int idx = tid; idx < 84 * 64; idx += 256) {
      int hh = idx >> 6, cc = idx & 63;
      tile[hh][cc] = y[(size_t)rtab[hh] * 256 + c0 + cc];
    }
    __syncthreads();
    for (int idx = tid; idx < 64 * 84; idx += 256) {
      int cc = idx / 84, hh = idx - cc * 84;
      out[((((size_t)b * 8 + d0) * 256 + c0 + cc) * 84 + w0) * 84 + hh] = tile[hh][cc];
    }
    __syncthreads();
  }
}

// ---------------- launch ----------------
extern "C" void kernel_launch(void* const* d_in, const int* in_sizes, int n_in,
                              void* d_out, int out_size, void* d_ws, size_t ws_size,
                              hipStream_t stream) {
  const float* x      = (const float*)d_in[0];
  const float* n1g    = (const float*)d_in[1];
  const float* n1b    = (const float*)d_in[2];
  const float* qkv_w  = (const float*)d_in[3];
  const float* rpb    = (const float*)d_in[4];
  const float* proj_w = (const float*)d_in[5];
  const float* proj_b = (const float*)d_in[6];
  const float* n2g    = (const float*)d_in[7];
  const float* n2b    = (const float*)d_in[8];
  const float* fc1_w  = (const float*)d_in[9];
  const float* fc1_b  = (const float*)d_in[10];
  const float* fc2_w  = (const float*)d_in[11];
  const float* fc2_b  = (const float*)d_in[12];
  float* out = (float*)d_out;

  // ---- persistent: weights + bias table ----
  char* w = (char*)d_ws;
  size_t off = 0;
  bf16* wq = (bf16*)(w + off); off += (size_t)768 * 256 * 2;
  bf16* wp = (bf16*)(w + off); off += (size_t)256 * 256 * 2;
  bf16* w1 = (bf16*)(w + off); off += (size_t)1024 * 256 * 2;
  bf16* w2 = (bf16*)(w + off); off += (size_t)1024 * 256 * 2;
  float* tbl = (float*)(w + off); off += (size_t)8 * 8 * 112 * 112 * 4;  // 3.2 MB

  // ---- per-chunk buffers (~274 MB total; known-good budget ~290 MB) ----
  float* xtw  = (float*)(w + off); off += (size_t)M2 * 1024;    // 57.8 MB (also y)
  bf16*  xw   = (bf16*)(w + off);  off += (size_t)M2 * 512;     // 28.9 MB (also aout)
  char*  qreg = w + off;           off += (size_t)M2 * 1536;    // 86.7 MB
  float* xres = (float*)(w + off); off += (size_t)M2 * 1024;    // 57.8 MB
  bf16*  hid  = (bf16*)(w + off);                               // sub-chunk sized
  bf16* qkvb = (bf16*)qreg;
  bf16* aout = xw;
  bf16* pout = (bf16*)qreg;
  bf16* ln2b = (bf16*)(qreg + (size_t)M2 * 512);
  float* ybuf = xtw;

  // MLP sub-chunk tiers: 147/49/21 row-tiles
  int subTiles = 21;
  if (off + (size_t)147 * 128 * 2048 + 1024 <= ws_size) subTiles = 147;
  else if (off + (size_t)49 * 128 * 2048 + 1024 <= ws_size) subTiles = 49;
  const int nsub = 441 / subTiles;
  const int MSUB = subTiles * 128;

  // weights -> bf16, bias table
  k_f2b<<<(196608 + 255) / 256, 256, 0, stream>>>(qkv_w, wq, 196608);
  k_f2b<<<(65536 + 255) / 256, 256, 0, stream>>>(proj_w, wp, 65536);
  k_f2b<<<(262144 + 255) / 256, 256, 0, stream>>>(fc1_w, w1, 262144);
  k_f2b<<<(262144 + 255) / 256, 256, 0, stream>>>(fc2_w, w2, 262144);
  k_bias<<<64, 256, 0, stream>>>(rpb, tbl);

  for (int c = 0; c < 2; ++c) {
    k_xpose_w<<<1344, 256, 0, stream>>>(x, xtw, c);
    k_ln1_lin<<<M2 / 4, 256, 0, stream>>>(xtw, n1g, n1b, xw);
    k_gemm_bt<0><<<441 * 6, 256, 0, stream>>>(xw, wq, M2, 768, 256, nullptr, nullptr, qkvb);
    k_attn_mfma<<<NWC * NH, 64, 0, stream>>>(qkvb, tbl, aout, 2 * c);
    k_gemm_bt<0><<<441 * 2, 256, 0, stream>>>(aout, wp, M2, 256, 256, proj_b, nullptr, pout);
    k_xres_ln2_lin<<<M2 / 4, 256, 0, stream>>>(xtw, pout, n2g, n2b, xres, ln2b);
    for (int s = 0; s < nsub; ++s) {
      size_t m0 = (size_t)s * MSUB;
      k_gemm_bt<1><<<subTiles * 8, 256, 0, stream>>>(
          ln2b + m0 * 256, w1, MSUB, 1024, 256, fc1_b, nullptr, hid);
      k_gemm_bt<2><<<subTiles * 2, 256, 0, stream>>>(
          hid, w2, MSUB, 256, 1024, fc2_b, xres + m0 * 256, ybuf + m0 * 256);
    }
    k_final_c<<<672, 256, 0, stream>>>(ybuf, out, c);
  }
}

// Round 8
// 855.129 us; speedup vs baseline: 1.4843x; 1.1815x over previous
//
#include <hip/hip_runtime.h>
#include <hip/hip_bf16.h>
#include <cstdint>
#include <cstddef>

// ---- problem constants ----
#define B_   2
#define D_   8
#define C_   256
#define W_   84
#define H_   84
#define NH   8
#define HD   32
#define NTOK 98
#define WH   7056        // W_*H_
#define M2   56448       // rows per chunk = 576 windows * 98 (441 * 128)
#define NWC  576         // windows per chunk

typedef __attribute__((ext_vector_type(8))) short sh8;
typedef __attribute__((ext_vector_type(4))) float f32x4;
typedef __hip_bfloat16 bf16;

// ---------------- fp32 -> bf16 weight convert ----------------
__global__ __launch_bounds__(256) void k_f2b(const float* __restrict__ in,
                                             bf16* __restrict__ out, int n) {
  int i = blockIdx.x * 256 + threadIdx.x;
  if (i < n) out[i] = __float2bfloat16(in[i]);
}

// ---------------- bias+mask table: [8 cls][8 h][112][112] f32 ----------------
__global__ __launch_bounds__(256) void k_bias(const float* __restrict__ rpb,
                                              float* __restrict__ tbl) {
  int cls = blockIdx.x >> 3, h = blockIdx.x & 7;
  int dB = cls >> 2, hB = (cls >> 1) & 1, wB = cls & 1;
  for (int idx = threadIdx.x; idx < 112 * 112; idx += 256) {
    int r = idx / 112, c = idx - (idx / 112) * 112;
    int rt = r < 98 ? r : 97, ct = c < 98 ? c : 97;
    int jdr = rt / 49, remr = rt % 49, jhr = remr / 7, jwr = remr % 7;
    int jdc = ct / 49, remc = ct % 49, jhc = remc / 7, jwc = remc % 7;
    int bir = jdr * 169 + jhr * 13 + jwr, bic = jdc * 169 + jhc * 13 + jwc;
    int dgr = dB ? ((6 + jdr) < 7 ? 1 : 2) : 0;
    int hgr = hB ? ((77 + jhr) < 81 ? 1 : 2) : 0;
    int wgr = wB ? ((77 + jwr) < 81 ? 1 : 2) : 0;
    int dgc = dB ? ((6 + jdc) < 7 ? 1 : 2) : 0;
    int hgc = hB ? ((77 + jhc) < 81 ? 1 : 2) : 0;
    int wgc = wB ? ((77 + jwc) < 81 ? 1 : 2) : 0;
    int cir = dgr * 9 + hgr * 3 + wgr, cic = dgc * 9 + hgc * 3 + wgc;
    float v = rpb[(bir - bic + 253) * 8 + h] + (cir == cic ? 0.f : -100.f);
    tbl[((size_t)(cls * 8 + h) * 112 + r) * 112 + c] = v;
  }
}

// inverse map: src/dst plane (b,d0,w0,h0) -> chunk-local row
__device__ __forceinline__ int inv_row(int b, int d0, int w0, int h0) {
  int sd = (d0 + 7) & 7;
  int lid = (sd >> 1) & 1, jd = sd & 1;
  int sh = h0 + 81; if (sh >= 84) sh -= 84;
  int sw = w0 + 81; if (sw >= 84) sw -= 84;
  int ih = sh / 7, jh = sh - ih * 7;
  int iw = sw / 7, jw = sw - iw * 7;
  return (b * 288 + lid * 144 + ih * 12 + iw) * 98 + jd * 49 + jh * 7 + jw;
}

// ---------------- x (B,D,C,W,H) -> xtw windowed rows x 256, f32 ----------------
__global__ __launch_bounds__(256) void k_xpose_w(const float* __restrict__ x,
                                                 float* __restrict__ xtw, int cchunk) {
  int blk = blockIdx.x;            // 1344 = 2ch * 84w * 4i * 2b
  int ch = blk & 1;
  int t = blk >> 1;
  int w0 = t % 84;
  int t2 = t / 84;
  int i = t2 & 3, b = t2 >> 2;
  int d0 = (cchunk * 4 + 1 + i) & 7;
  __shared__ float tile[128][85];
  __shared__ int rtab[84];
  int tid = threadIdx.x;
  if (tid < 84) rtab[tid] = inv_row(b, d0, w0, tid);
  const float* src = x + ((size_t)(b * 8 + d0) * 256 + ch * 128) * WH + w0 * 84;
  for (int idx = tid; idx < 128 * 21; idx += 256) {
    int c = idx / 21, h4 = idx - c * 21;
    float4 v = *(const float4*)(src + (size_t)c * WH + h4 * 4);
    tile[c][h4 * 4 + 0] = v.x; tile[c][h4 * 4 + 1] = v.y;
    tile[c][h4 * 4 + 2] = v.z; tile[c][h4 * 4 + 3] = v.w;
  }
  __syncthreads();
  for (int idx = tid; idx < 84 * 128; idx += 256) {
    int h = idx >> 7, cc = idx & 127;
    xtw[(size_t)rtab[h] * 256 + ch * 128 + cc] = tile[cc][h];
  }
}

// ---------------- LN1: linear streaming ----------------
__global__ __launch_bounds__(256) void k_ln1_lin(
    const float* __restrict__ xtw, const float* __restrict__ g,
    const float* __restrict__ bb, bf16* __restrict__ xw) {
  int rl = blockIdx.x * 4 + (threadIdx.x >> 6);
  int lane = threadIdx.x & 63;
  int c0 = lane * 4;
  float4 v = *(const float4*)(xtw + (size_t)rl * 256 + c0);
  float s = v.x + v.y + v.z + v.w;
  float s2 = v.x * v.x + v.y * v.y + v.z * v.z + v.w * v.w;
#pragma unroll
  for (int off = 32; off; off >>= 1) { s += __shfl_xor(s, off, 64); s2 += __shfl_xor(s2, off, 64); }
  float mu = s * (1.f / 256.f);
  float var = s2 * (1.f / 256.f) - mu * mu;
  float rs = rsqrtf(var + 1e-5f);
  float4 gg = *(const float4*)(g + c0);
  float4 bv = *(const float4*)(bb + c0);
  bf16 tmp[4];
  tmp[0] = __float2bfloat16((v.x - mu) * rs * gg.x + bv.x);
  tmp[1] = __float2bfloat16((v.y - mu) * rs * gg.y + bv.y);
  tmp[2] = __float2bfloat16((v.z - mu) * rs * gg.z + bv.z);
  tmp[3] = __float2bfloat16((v.w - mu) * rs * gg.w + bv.w);
  *(ushort4*)(&xw[(size_t)rl * 256 + c0]) = *(ushort4*)tmp;
}

// fast exact-GELU: erf via Abramowitz-Stegun 7.1.26 (|err| ~ 3e-7)
__device__ __forceinline__ float gelu_fast(float v) {
  float x = v * 0.70710678118f;
  float ax = fabsf(x);
  float t = 1.0f / (1.0f + 0.3275911f * ax);
  float y = t * (0.254829592f + t * (-0.284496736f +
            t * (1.421413741f + t * (-1.453152027f + t * 1.061405429f))));
  float er = 1.0f - y * __expf(-ax * ax);
  er = copysignf(er, x);
  return 0.5f * v * (1.0f + er);
}

// ---------------- bf16 B^T GEMM: dbuf global_load_lds + XCD-aware block swizzle ----------------
// LDS: linear [row][64] shorts, content XOR-swizzled (chunk ^= row&7) via pre-swizzled
// global SOURCE address; ds_read applies the same XOR (conflict-free, verified R7: 0 conflicts).
// Block swizzle (T1/m204 bijective): contiguous (bm,bn) ranges per XCD -> A-panel L2 reuse.
// EPI 0: (+bias) -> bf16   EPI 1: +bias, GELU -> bf16   EPI 2: +bias +res -> f32 linear
template <int EPI>
__global__ __launch_bounds__(256) void k_gemm_bt(
    const bf16* __restrict__ A, const bf16* __restrict__ Bw,
    int M, int N, int K,
    const float* __restrict__ bias, const float* __restrict__ res,
    void* __restrict__ outv) {
  __shared__ __align__(16) short smem[32768];   // 64 KB: 2 bufs x (sA 8192 | sB 8192)
  // ---- bijective XCD swizzle ----
  int nwg = gridDim.x;
  int orig = blockIdx.x;
  int q8 = nwg >> 3, r8 = nwg & 7;
  int xcd = orig & 7, lwg = orig >> 3;
  int bid = (xcd < r8 ? xcd * (q8 + 1) : r8 * (q8 + 1) + (xcd - r8) * q8) + lwg;
  int nbn = N >> 7;
  int bm = bid / nbn, bn = bid - bm * nbn;
  int tid = threadIdx.x;
  int lane = tid & 63, wv = tid >> 6;
  int wr = wv >> 1, wc = wv & 1;
  f32x4 acc[4][4] = {};
  const short* Ag = (const short*)A + (size_t)bm * 128 * K;
  const short* Bg = (const short*)Bw + (size_t)bn * 128 * K;
  int rA = wv * 32 + (lane >> 3);
  int cSrc = ((lane & 7) ^ ((lane >> 3) & 7)) * 8;   // shorts
  int nk = K >> 6;

  auto stage = [&](int buf, int kt) {
    short* sA = smem + buf * 16384;
    short* sB = sA + 8192;
    const short* ga = Ag + (size_t)rA * K + kt * 64 + cSrc;
    const short* gb = Bg + (size_t)rA * K + kt * 64 + cSrc;
#pragma unroll
    for (int rr = 0; rr < 4; ++rr) {
      __builtin_amdgcn_global_load_lds(
          (const __attribute__((address_space(1))) void*)(ga + (size_t)rr * 8 * K),
          (__attribute__((address_space(3))) void*)&sA[(wv * 32 + rr * 8) * 64], 16, 0, 0);
      __builtin_amdgcn_global_load_lds(
          (const __attribute__((address_space(1))) void*)(gb + (size_t)rr * 8 * K),
          (__attribute__((address_space(3))) void*)&sB[(wv * 32 + rr * 8) * 64], 16, 0, 0);
    }
  };

  stage(0, 0);
  __syncthreads();
  int cur = 0;
  for (int kt = 0; kt < nk; ++kt) {
    if (kt + 1 < nk) stage(cur ^ 1, kt + 1);   // prefetch before compute
    const short* sA = smem + cur * 16384;
    const short* sB = sA + 8192;
#pragma unroll
    for (int ks = 0; ks < 2; ++ks) {
      sh8 af[4], bfr[4];
      int rb = wr * 64 + (lane & 15);
      int cb = wc * 64 + (lane & 15);
      int kswz = ((ks * 4 + (lane >> 4)) ^ (lane & 7)) * 8;
#pragma unroll
      for (int m = 0; m < 4; ++m) af[m] = *(const sh8*)&sA[(rb + m * 16) * 64 + kswz];
#pragma unroll
      for (int n2 = 0; n2 < 4; ++n2) bfr[n2] = *(const sh8*)&sB[(cb + n2 * 16) * 64 + kswz];
#pragma unroll
      for (int m = 0; m < 4; ++m)
#pragma unroll
        for (int n2 = 0; n2 < 4; ++n2)
          acc[m][n2] = __builtin_amdgcn_mfma_f32_16x16x32_bf16(af[m], bfr[n2], acc[m][n2], 0, 0, 0);
    }
    if (kt + 1 < nk) __syncthreads();
    cur ^= 1;
  }
  // direct epilogue
  int rbase = bm * 128 + wr * 64 + ((lane >> 4) << 2);
  int cbase = bn * 128 + wc * 64 + (lane & 15);
#pragma unroll
  for (int m = 0; m < 4; ++m) {
#pragma unroll
    for (int j = 0; j < 4; ++j) {
      int r = rbase + m * 16 + j;
#pragma unroll
      for (int n2 = 0; n2 < 4; ++n2) {
        int cc = cbase + n2 * 16;
        float v = acc[m][n2][j];
        if (EPI == 2) {
          v += bias[cc] + res[(size_t)r * N + cc];
          ((float*)outv)[(size_t)r * N + cc] = v;
        } else {
          if (bias) v += bias[cc];
          if (EPI == 1) v = gelu_fast(v);
          ((bf16*)outv)[(size_t)r * N + cc] = __float2bfloat16(v);
        }
      }
    }
  }
}

// ---------------- MFMA windowed attention: 1 wave per (window, head) ----------------
__global__ __launch_bounds__(64) void k_attn_mfma(
    const bf16* __restrict__ qkv, const float* __restrict__ tbl,
    bf16* __restrict__ aout, int idbase) {
  int blk = blockIdx.x;
  int wl = blk >> 3, h = blk & 7;
  int lid = (wl / 144) & 1;
  int id = idbase + lid;
  int rem = wl % 144;
  int ih = rem / 12, iw = rem - ih * 12;
  int cls = ((id == 3) ? 4 : 0) + ((ih == 11) ? 2 : 0) + ((iw == 11) ? 1 : 0);
  const float* bt = tbl + (size_t)(cls * 8 + h) * 112 * 112;
  int lane = threadIdx.x;
  __shared__ __align__(16) short vt[32][136];   // V^T, padded
  __shared__ __align__(16) short pb[16][136];   // P band
  sh8 z = {};
  for (int i = lane; i < 544; i += 64) *((sh8*)&vt[0][0] + i) = z;
  for (int i = lane; i < 272; i += 64) *((sh8*)&pb[0][0] + i) = z;
  __syncthreads();
  const size_t base = (size_t)wl * NTOK * 768;
  for (int i = lane; i < 98 * 8; i += 64) {
    int c = i >> 3, d4 = (i & 7) * 4;
    ushort4 vu = *(const ushort4*)&qkv[base + (size_t)c * 768 + 512 + h * 32 + d4];
    vt[d4 + 0][c] = (short)vu.x; vt[d4 + 1][c] = (short)vu.y;
    vt[d4 + 2][c] = (short)vu.z; vt[d4 + 3][c] = (short)vu.w;
  }
  int kq = (lane >> 4) * 8;
  sh8 kf[7];
#pragma unroll
  for (int jt = 0; jt < 7; ++jt) {
    int c = jt * 16 + (lane & 15);
    kf[jt] = *(const sh8*)&qkv[base + (size_t)c * 768 + 256 + h * 32 + kq];
  }
  __syncthreads();
  sh8 vb[2][4];
#pragma unroll
  for (int dt = 0; dt < 2; ++dt)
#pragma unroll
    for (int k2 = 0; k2 < 4; ++k2)
      vb[dt][k2] = *(const sh8*)&vt[dt * 16 + (lane & 15)][k2 * 32 + kq];

  const float scale = 0.17677669529663687f;
  f32x4 zc = {};
  int rband = (lane >> 4) * 4;
  for (int it = 0; it < 7; ++it) {
    int rq = it * 16 + (lane & 15);
    sh8 qf = *(const sh8*)&qkv[base + (size_t)rq * 768 + h * 32 + kq];
    f32x4 s[7];
#pragma unroll
    for (int jt = 0; jt < 7; ++jt)
      s[jt] = __builtin_amdgcn_mfma_f32_16x16x32_bf16(qf, kf[jt], zc, 0, 0, 0);
    float p[7][4], linv[4];
#pragma unroll
    for (int j = 0; j < 4; ++j) {
      int r2 = it * 16 + rband + j;
      float rs = 0.f;
#pragma unroll
      for (int jt = 0; jt < 7; ++jt) {
        int c = jt * 16 + (lane & 15);
        float v = s[jt][j] * scale + bt[r2 * 112 + c];
        float e = __expf(v);
        if (jt == 6 && (lane & 15) >= 2) e = 0.f;
        p[jt][j] = e;
        rs += e;
      }
      rs += __shfl_xor(rs, 1, 64); rs += __shfl_xor(rs, 2, 64);
      rs += __shfl_xor(rs, 4, 64); rs += __shfl_xor(rs, 8, 64);
      linv[j] = 1.f / rs;
    }
#pragma unroll
    for (int j = 0; j < 4; ++j)
#pragma unroll
      for (int jt = 0; jt < 7; ++jt) {
        bf16 bv = __float2bfloat16(p[jt][j] * linv[j]);
        pb[rband + j][jt * 16 + (lane & 15)] = *(short*)&bv;
      }
    __syncthreads();
    sh8 pa[4];
#pragma unroll
    for (int k2 = 0; k2 < 4; ++k2)
      pa[k2] = *(const sh8*)&pb[lane & 15][k2 * 32 + kq];
    f32x4 o[2] = {};
#pragma unroll
    for (int dt = 0; dt < 2; ++dt)
#pragma unroll
      for (int k2 = 0; k2 < 4; ++k2)
        o[dt] = __builtin_amdgcn_mfma_f32_16x16x32_bf16(pa[k2], vb[dt][k2], o[dt], 0, 0, 0);
#pragma unroll
    for (int j = 0; j < 4; ++j) {
      int r2 = it * 16 + rband + j;
      if (r2 < 98) {
#pragma unroll
        for (int dt = 0; dt < 2; ++dt) {
          bf16 ov = __float2bfloat16(o[dt][j]);
          aout[((size_t)wl * 98 + r2) * 256 + h * 32 + dt * 16 + (lane & 15)] = ov;
        }
      }
    }
    __syncthreads();
  }
}

// ---------------- residual + LN2: linear streaming ----------------
__global__ __launch_bounds__(256) void k_xres_ln2_lin(
    const float* __restrict__ xtw, const bf16* __restrict__ pout,
    const float* __restrict__ g, const float* __restrict__ bb,
    float* __restrict__ xres, bf16* __restrict__ ln2) {
  int rl = blockIdx.x * 4 + (threadIdx.x >> 6);
  int lane = threadIdx.x & 63;
  int c0 = lane * 4;
  float4 v = *(const float4*)(xtw + (size_t)rl * 256 + c0);
  ushort4 pu = *(const ushort4*)(pout + (size_t)rl * 256 + c0);
  v.x += __bfloat162float(*(bf16*)&pu.x);
  v.y += __bfloat162float(*(bf16*)&pu.y);
  v.z += __bfloat162float(*(bf16*)&pu.z);
  v.w += __bfloat162float(*(bf16*)&pu.w);
  *(float4*)(xres + (size_t)rl * 256 + c0) = v;
  float s = v.x + v.y + v.z + v.w;
  float s2 = v.x * v.x + v.y * v.y + v.z * v.z + v.w * v.w;
#pragma unroll
  for (int off = 32; off; off >>= 1) { s += __shfl_xor(s, off, 64); s2 += __shfl_xor(s2, off, 64); }
  float mu = s * (1.f / 256.f);
  float var = s2 * (1.f / 256.f) - mu * mu;
  float rs = rsqrtf(var + 1e-5f);
  float4 gg = *(const float4*)(g + c0);
  float4 bv = *(const float4*)(bb + c0);
  bf16 tmp[4];
  tmp[0] = __float2bfloat16((v.x - mu) * rs * gg.x + bv.x);
  tmp[1] = __float2bfloat16((v.y - mu) * rs * gg.y + bv.y);
  tmp[2] = __float2bfloat16((v.z - mu) * rs * gg.z + bv.z);
  tmp[3] = __float2bfloat16((v.w - mu) * rs * gg.w + bv.w);
  *(ushort4*)(&ln2[(size_t)rl * 256 + c0]) = *(ushort4*)tmp;
}

// ---------------- final: chunk-local y (f32 windowed) -> (B,D,C,W,H) ----------------
__global__ __launch_bounds__(256) void k_final_c(const float* __restrict__ y,
                                                 float* __restrict__ out, int cchunk) {
  int t = blockIdx.x;              // 672 = 84w * 4i * 2b
  int w0 = t % 84;
  int t2 = t / 84;
  int i = t2 & 3, b = t2 >> 2;
  int d0 = (cchunk * 4 + 1 + i) & 7;
  __shared__ float tile[84][65];
  __shared__ int rtab[84];
  int tid = threadIdx.x;
  if (tid < 84) rtab[tid] = inv_row(b, d0, w0, tid);
  __syncthreads();
  for (int c0 = 0; c0 < 256; c0 += 64) {
    for (int idx = tid; idx < 84 * 64; idx += 256) {
      int hh = idx >> 6, cc = idx & 63;
      tile[hh][cc] = y[(size_t)rtab[hh] * 256 + c0 + cc];
    }
    __syncthreads();
    for (int idx = tid; idx < 64 * 84; idx += 256) {
      int cc = idx / 84, hh = idx - cc * 84;
      out[((((size_t)b * 8 + d0) * 256 + c0 + cc) * 84 + w0) * 84 + hh] = tile[hh][cc];
    }
    __syncthreads();
  }
}

// ---------------- launch ----------------
extern "C" void kernel_launch(void* const* d_in, const int* in_sizes, int n_in,
                              void* d_out, int out_size, void* d_ws, size_t ws_size,
                              hipStream_t stream) {
  const float* x      = (const float*)d_in[0];
  const float* n1g    = (const float*)d_in[1];
  const float* n1b    = (const float*)d_in[2];
  const float* qkv_w  = (const float*)d_in[3];
  const float* rpb    = (const float*)d_in[4];
  const float* proj_w = (const float*)d_in[5];
  const float* proj_b = (const float*)d_in[6];
  const float* n2g    = (const float*)d_in[7];
  const float* n2b    = (const float*)d_in[8];
  const float* fc1_w  = (const float*)d_in[9];
  const float* fc1_b  = (const float*)d_in[10];
  const float* fc2_w  = (const float*)d_in[11];
  const float* fc2_b  = (const float*)d_in[12];
  float* out = (float*)d_out;

  // ---- persistent: weights + bias table ----
  char* w = (char*)d_ws;
  size_t off = 0;
  bf16* wq = (bf16*)(w + off); off += (size_t)768 * 256 * 2;
  bf16* wp = (bf16*)(w + off); off += (size_t)256 * 256 * 2;
  bf16* w1 = (bf16*)(w + off); off += (size_t)1024 * 256 * 2;
  bf16* w2 = (bf16*)(w + off); off += (size_t)1024 * 256 * 2;
  float* tbl = (float*)(w + off); off += (size_t)8 * 8 * 112 * 112 * 4;  // 3.2 MB

  // ---- per-chunk buffers ----
  float* xtw  = (float*)(w + off); off += (size_t)M2 * 1024;    // 57.8 MB (also y)
  bf16*  xw   = (bf16*)(w + off);  off += (size_t)M2 * 512;     // 28.9 MB (also aout)
  char*  qreg = w + off;           off += (size_t)M2 * 1536;    // 86.7 MB
  float* xres = (float*)(w + off); off += (size_t)M2 * 1024;    // 57.8 MB
  bf16*  hid  = (bf16*)(w + off);                               // tier-sized
  bf16* qkvb = (bf16*)qreg;
  bf16* aout = xw;
  bf16* pout = (bf16*)qreg;
  bf16* ln2b = (bf16*)(qreg + (size_t)M2 * 512);
  float* ybuf = xtw;

  // MLP tiers: full 441 (hid 115.6 MB; ws>=441MB measured via poison fill) / 147 / 49 / 21
  int subTiles = 21;
  if (off + (size_t)441 * 128 * 2048 + 1024 <= ws_size) subTiles = 441;
  else if (off + (size_t)147 * 128 * 2048 + 1024 <= ws_size) subTiles = 147;
  else if (off + (size_t)49 * 128 * 2048 + 1024 <= ws_size) subTiles = 49;
  const int nsub = 441 / subTiles;
  const int MSUB = subTiles * 128;

  // weights -> bf16, bias table
  k_f2b<<<(196608 + 255) / 256, 256, 0, stream>>>(qkv_w, wq, 196608);
  k_f2b<<<(65536 + 255) / 256, 256, 0, stream>>>(proj_w, wp, 65536);
  k_f2b<<<(262144 + 255) / 256, 256, 0, stream>>>(fc1_w, w1, 262144);
  k_f2b<<<(262144 + 255) / 256, 256, 0, stream>>>(fc2_w, w2, 262144);
  k_bias<<<64, 256, 0, stream>>>(rpb, tbl);

  for (int c = 0; c < 2; ++c) {
    k_xpose_w<<<1344, 256, 0, stream>>>(x, xtw, c);
    k_ln1_lin<<<M2 / 4, 256, 0, stream>>>(xtw, n1g, n1b, xw);
    k_gemm_bt<0><<<441 * 6, 256, 0, stream>>>(xw, wq, M2, 768, 256, nullptr, nullptr, qkvb);
    k_attn_mfma<<<NWC * NH, 64, 0, stream>>>(qkvb, tbl, aout, 2 * c);
    k_gemm_bt<0><<<441 * 2, 256, 0, stream>>>(aout, wp, M2, 256, 256, proj_b, nullptr, pout);
    k_xres_ln2_lin<<<M2 / 4, 256, 0, stream>>>(xtw, pout, n2g, n2b, xres, ln2b);
    for (int s = 0; s < nsub; ++s) {
      size_t m0 = (size_t)s * MSUB;
      k_gemm_bt<1><<<subTiles * 8, 256, 0, stream>>>(
          ln2b + m0 * 256, w1, MSUB, 1024, 256, fc1_b, nullptr, hid);
      k_gemm_bt<2><<<subTiles * 2, 256, 0, stream>>>(
          hid, w2, MSUB, 256, 1024, fc2_b, xres + m0 * 256, ybuf + m0 * 256);
    }
    k_final_c<<<672, 256, 0, stream>>>(ybuf, out, c);
  }
}

// Round 9
// 805.777 us; speedup vs baseline: 1.5752x; 1.0612x over previous
//
#include <hip/hip_runtime.h>
#include <hip/hip_bf16.h>
#include <cstdint>
#include <cstddef>

// ---- problem constants ----
#define B_   2
#define D_   8
#define C_   256
#define W_   84
#define H_   84
#define NH   8
#define HD   32
#define NTOK 98
#define WH   7056        // W_*H_
#define M2   56448       // rows per chunk = 576 windows * 98 (441 * 128)
#define NWC  576         // windows per chunk

typedef __attribute__((ext_vector_type(8))) short sh8;
typedef __attribute__((ext_vector_type(4))) float f32x4;
typedef __hip_bfloat16 bf16;

// ---------------- fp32 -> bf16 weight convert ----------------
__global__ __launch_bounds__(256) void k_f2b(const float* __restrict__ in,
                                             bf16* __restrict__ out, int n) {
  int i = blockIdx.x * 256 + threadIdx.x;
  if (i < n) out[i] = __float2bfloat16(in[i]);
}

// ---------------- bias+mask table: [8 cls][8 h][112][112] f32 ----------------
__global__ __launch_bounds__(256) void k_bias(const float* __restrict__ rpb,
                                              float* __restrict__ tbl) {
  int cls = blockIdx.x >> 3, h = blockIdx.x & 7;
  int dB = cls >> 2, hB = (cls >> 1) & 1, wB = cls & 1;
  for (int idx = threadIdx.x; idx < 112 * 112; idx += 256) {
    int r = idx / 112, c = idx - (idx / 112) * 112;
    int rt = r < 98 ? r : 97, ct = c < 98 ? c : 97;
    int jdr = rt / 49, remr = rt % 49, jhr = remr / 7, jwr = remr % 7;
    int jdc = ct / 49, remc = ct % 49, jhc = remc / 7, jwc = remc % 7;
    int bir = jdr * 169 + jhr * 13 + jwr, bic = jdc * 169 + jhc * 13 + jwc;
    int dgr = dB ? ((6 + jdr) < 7 ? 1 : 2) : 0;
    int hgr = hB ? ((77 + jhr) < 81 ? 1 : 2) : 0;
    int wgr = wB ? ((77 + jwr) < 81 ? 1 : 2) : 0;
    int dgc = dB ? ((6 + jdc) < 7 ? 1 : 2) : 0;
    int hgc = hB ? ((77 + jhc) < 81 ? 1 : 2) : 0;
    int wgc = wB ? ((77 + jwc) < 81 ? 1 : 2) : 0;
    int cir = dgr * 9 + hgr * 3 + wgr, cic = dgc * 9 + hgc * 3 + wgc;
    float v = rpb[(bir - bic + 253) * 8 + h] + (cir == cic ? 0.f : -100.f);
    tbl[((size_t)(cls * 8 + h) * 112 + r) * 112 + c] = v;
  }
}

// inverse map: src/dst plane (b,d0,w0,h0) -> chunk-local row
__device__ __forceinline__ int inv_row(int b, int d0, int w0, int h0) {
  int sd = (d0 + 7) & 7;
  int lid = (sd >> 1) & 1, jd = sd & 1;
  int sh = h0 + 81; if (sh >= 84) sh -= 84;
  int sw = w0 + 81; if (sw >= 84) sw -= 84;
  int ih = sh / 7, jh = sh - ih * 7;
  int iw = sw / 7, jw = sw - iw * 7;
  return (b * 288 + lid * 144 + ih * 12 + iw) * 98 + jd * 49 + jh * 7 + jw;
}

// ---------------- x (B,D,C,W,H) -> xtw windowed rows x 256, f32 ----------------
__global__ __launch_bounds__(256) void k_xpose_w(const float* __restrict__ x,
                                                 float* __restrict__ xtw, int cchunk) {
  int blk = blockIdx.x;            // 1344 = 2ch * 84w * 4i * 2b
  int ch = blk & 1;
  int t = blk >> 1;
  int w0 = t % 84;
  int t2 = t / 84;
  int i = t2 & 3, b = t2 >> 2;
  int d0 = (cchunk * 4 + 1 + i) & 7;
  __shared__ float tile[128][85];
  __shared__ int rtab[84];
  int tid = threadIdx.x;
  if (tid < 84) rtab[tid] = inv_row(b, d0, w0, tid);
  const float* src = x + ((size_t)(b * 8 + d0) * 256 + ch * 128) * WH + w0 * 84;
  for (int idx = tid; idx < 128 * 21; idx += 256) {
    int c = idx / 21, h4 = idx - c * 21;
    float4 v = *(const float4*)(src + (size_t)c * WH + h4 * 4);
    tile[c][h4 * 4 + 0] = v.x; tile[c][h4 * 4 + 1] = v.y;
    tile[c][h4 * 4 + 2] = v.z; tile[c][h4 * 4 + 3] = v.w;
  }
  __syncthreads();
  for (int idx = tid; idx < 84 * 128; idx += 256) {
    int h = idx >> 7, cc = idx & 127;
    xtw[(size_t)rtab[h] * 256 + ch * 128 + cc] = tile[cc][h];
  }
}

// ---------------- LN1: linear streaming ----------------
__global__ __launch_bounds__(256) void k_ln1_lin(
    const float* __restrict__ xtw, const float* __restrict__ g,
    const float* __restrict__ bb, bf16* __restrict__ xw) {
  int rl = blockIdx.x * 4 + (threadIdx.x >> 6);
  int lane = threadIdx.x & 63;
  int c0 = lane * 4;
  float4 v = *(const float4*)(xtw + (size_t)rl * 256 + c0);
  float s = v.x + v.y + v.z + v.w;
  float s2 = v.x * v.x + v.y * v.y + v.z * v.z + v.w * v.w;
#pragma unroll
  for (int off = 32; off; off >>= 1) { s += __shfl_xor(s, off, 64); s2 += __shfl_xor(s2, off, 64); }
  float mu = s * (1.f / 256.f);
  float var = s2 * (1.f / 256.f) - mu * mu;
  float rs = rsqrtf(var + 1e-5f);
  float4 gg = *(const float4*)(g + c0);
  float4 bv = *(const float4*)(bb + c0);
  bf16 tmp[4];
  tmp[0] = __float2bfloat16((v.x - mu) * rs * gg.x + bv.x);
  tmp[1] = __float2bfloat16((v.y - mu) * rs * gg.y + bv.y);
  tmp[2] = __float2bfloat16((v.z - mu) * rs * gg.z + bv.z);
  tmp[3] = __float2bfloat16((v.w - mu) * rs * gg.w + bv.w);
  *(ushort4*)(&xw[(size_t)rl * 256 + c0]) = *(ushort4*)tmp;
}

// fast exact-GELU: erf via Abramowitz-Stegun 7.1.26 (|err| ~ 3e-7)
__device__ __forceinline__ float gelu_fast(float v) {
  float x = v * 0.70710678118f;
  float ax = fabsf(x);
  float t = 1.0f / (1.0f + 0.3275911f * ax);
  float y = t * (0.254829592f + t * (-0.284496736f +
            t * (1.421413741f + t * (-1.453152027f + t * 1.061405429f))));
  float er = 1.0f - y * __expf(-ax * ax);
  er = copysignf(er, x);
  return 0.5f * v * (1.0f + er);
}

// ---------------- bf16 B^T GEMM: BK=32 dbuf (32KB LDS -> 4-5 blocks/CU) ----------------
// LDS: linear [row][32] shorts (64B rows = 4x16B chunks), content XOR-swizzled
// (chunk ^= row&3) via pre-swizzled global SOURCE; ds_read applies the same XOR.
// Slot check: (4*rb + q^(rb&3))%8 covers each 16B slot exactly 8x -> conflict-free.
// Block swizzle (T1/m204 bijective) for A-panel L2 reuse (verified R8: FETCH 38->16.5MB).
// EPI 0: (+bias) -> bf16   EPI 1: +bias, GELU -> bf16   EPI 2: +bias +res -> f32 linear
template <int EPI>
__global__ __launch_bounds__(256) void k_gemm_bt(
    const bf16* __restrict__ A, const bf16* __restrict__ Bw,
    int M, int N, int K,
    const float* __restrict__ bias, const float* __restrict__ res,
    void* __restrict__ outv) {
  __shared__ __align__(16) short smem[16384];   // 32 KB: 2 bufs x (sA 4096 | sB 4096 shorts)
  // ---- bijective XCD swizzle ----
  int nwg = gridDim.x;
  int orig = blockIdx.x;
  int q8 = nwg >> 3, r8 = nwg & 7;
  int xcd = orig & 7, lwg = orig >> 3;
  int bid = (xcd < r8 ? xcd * (q8 + 1) : r8 * (q8 + 1) + (xcd - r8) * q8) + lwg;
  int nbn = N >> 7;
  int bm = bid / nbn, bn = bid - bm * nbn;
  int tid = threadIdx.x;
  int lane = tid & 63, wv = tid >> 6;
  int wr = wv >> 1, wc = wv & 1;
  f32x4 acc[4][4] = {};
  const short* Ag = (const short*)A + (size_t)bm * 128 * K;
  const short* Bg = (const short*)Bw + (size_t)bn * 128 * K;
  // staging: wave wv covers rows wv*32..+31 in 2 groups of 16; lane l -> row +(l>>2),
  // dest chunk l&3; source chunk = (l&3) ^ (row&3) = (l&3) ^ ((l>>2)&3)
  int rIn = lane >> 2;
  int cSrc = ((lane & 3) ^ (rIn & 3)) * 8;   // shorts
  int nk = K >> 5;

  auto stage = [&](int buf, int kt) {
    short* sA = smem + buf * 8192;
    short* sB = sA + 4096;
#pragma unroll
    for (int rr = 0; rr < 2; ++rr) {
      int r0 = wv * 32 + rr * 16;
      const short* ga = Ag + (size_t)(r0 + rIn) * K + kt * 32 + cSrc;
      const short* gb = Bg + (size_t)(r0 + rIn) * K + kt * 32 + cSrc;
      __builtin_amdgcn_global_load_lds(
          (const __attribute__((address_space(1))) void*)ga,
          (__attribute__((address_space(3))) void*)&sA[r0 * 32], 16, 0, 0);
      __builtin_amdgcn_global_load_lds(
          (const __attribute__((address_space(1))) void*)gb,
          (__attribute__((address_space(3))) void*)&sB[r0 * 32], 16, 0, 0);
    }
  };

  stage(0, 0);
  __syncthreads();
  int cur = 0;
  int rb = wr * 64 + (lane & 15);
  int cb = wc * 64 + (lane & 15);
  int kswz = ((lane >> 4) ^ (lane & 3)) * 8;   // swizzled 16B chunk (row&3 == lane&3)
  for (int kt = 0; kt < nk; ++kt) {
    if (kt + 1 < nk) stage(cur ^ 1, kt + 1);   // prefetch before compute
    const short* sA = smem + cur * 8192;
    const short* sB = sA + 4096;
    sh8 af[4], bfr[4];
#pragma unroll
    for (int m = 0; m < 4; ++m) af[m] = *(const sh8*)&sA[(rb + m * 16) * 32 + kswz];
#pragma unroll
    for (int n2 = 0; n2 < 4; ++n2) bfr[n2] = *(const sh8*)&sB[(cb + n2 * 16) * 32 + kswz];
#pragma unroll
    for (int m = 0; m < 4; ++m)
#pragma unroll
      for (int n2 = 0; n2 < 4; ++n2)
        acc[m][n2] = __builtin_amdgcn_mfma_f32_16x16x32_bf16(af[m], bfr[n2], acc[m][n2], 0, 0, 0);
    if (kt + 1 < nk) __syncthreads();
    cur ^= 1;
  }
  // direct epilogue
  int rbase = bm * 128 + wr * 64 + ((lane >> 4) << 2);
  int cbase = bn * 128 + wc * 64 + (lane & 15);
#pragma unroll
  for (int m = 0; m < 4; ++m) {
#pragma unroll
    for (int j = 0; j < 4; ++j) {
      int r = rbase + m * 16 + j;
#pragma unroll
      for (int n2 = 0; n2 < 4; ++n2) {
        int cc = cbase + n2 * 16;
        float v = acc[m][n2][j];
        if (EPI == 2) {
          v += bias[cc] + res[(size_t)r * N + cc];
          ((float*)outv)[(size_t)r * N + cc] = v;
        } else {
          if (bias) v += bias[cc];
          if (EPI == 1) v = gelu_fast(v);
          ((bf16*)outv)[(size_t)r * N + cc] = __float2bfloat16(v);
        }
      }
    }
  }
}

// ---------------- MFMA windowed attention: 1 wave per (window, head) ----------------
__global__ __launch_bounds__(64) void k_attn_mfma(
    const bf16* __restrict__ qkv, const float* __restrict__ tbl,
    bf16* __restrict__ aout, int idbase) {
  int blk = blockIdx.x;
  int wl = blk >> 3, h = blk & 7;
  int lid = (wl / 144) & 1;
  int id = idbase + lid;
  int rem = wl % 144;
  int ih = rem / 12, iw = rem - ih * 12;
  int cls = ((id == 3) ? 4 : 0) + ((ih == 11) ? 2 : 0) + ((iw == 11) ? 1 : 0);
  const float* bt = tbl + (size_t)(cls * 8 + h) * 112 * 112;
  int lane = threadIdx.x;
  __shared__ __align__(16) short vt[32][136];   // V^T, padded
  __shared__ __align__(16) short pb[16][136];   // P band
  sh8 z = {};
  for (int i = lane; i < 544; i += 64) *((sh8*)&vt[0][0] + i) = z;
  for (int i = lane; i < 272; i += 64) *((sh8*)&pb[0][0] + i) = z;
  __syncthreads();
  const size_t base = (size_t)wl * NTOK * 768;
  for (int i = lane; i < 98 * 8; i += 64) {
    int c = i >> 3, d4 = (i & 7) * 4;
    ushort4 vu = *(const ushort4*)&qkv[base + (size_t)c * 768 + 512 + h * 32 + d4];
    vt[d4 + 0][c] = (short)vu.x; vt[d4 + 1][c] = (short)vu.y;
    vt[d4 + 2][c] = (short)vu.z; vt[d4 + 3][c] = (short)vu.w;
  }
  int kq = (lane >> 4) * 8;
  sh8 kf[7];
#pragma unroll
  for (int jt = 0; jt < 7; ++jt) {
    int c = jt * 16 + (lane & 15);
    kf[jt] = *(const sh8*)&qkv[base + (size_t)c * 768 + 256 + h * 32 + kq];
  }
  __syncthreads();
  sh8 vb[2][4];
#pragma unroll
  for (int dt = 0; dt < 2; ++dt)
#pragma unroll
    for (int k2 = 0; k2 < 4; ++k2)
      vb[dt][k2] = *(const sh8*)&vt[dt * 16 + (lane & 15)][k2 * 32 + kq];

  const float scale = 0.17677669529663687f;
  f32x4 zc = {};
  int rband = (lane >> 4) * 4;
  for (int it = 0; it < 7; ++it) {
    int rq = it * 16 + (lane & 15);
    sh8 qf = *(const sh8*)&qkv[base + (size_t)rq * 768 + h * 32 + kq];
    f32x4 s[7];
#pragma unroll
    for (int jt = 0; jt < 7; ++jt)
      s[jt] = __builtin_amdgcn_mfma_f32_16x16x32_bf16(qf, kf[jt], zc, 0, 0, 0);
    float p[7][4], linv[4];
#pragma unroll
    for (int j = 0; j < 4; ++j) {
      int r2 = it * 16 + rband + j;
      float rs = 0.f;
#pragma unroll
      for (int jt = 0; jt < 7; ++jt) {
        int c = jt * 16 + (lane & 15);
        float v = s[jt][j] * scale + bt[r2 * 112 + c];
        float e = __expf(v);
        if (jt == 6 && (lane & 15) >= 2) e = 0.f;
        p[jt][j] = e;
        rs += e;
      }
      rs += __shfl_xor(rs, 1, 64); rs += __shfl_xor(rs, 2, 64);
      rs += __shfl_xor(rs, 4, 64); rs += __shfl_xor(rs, 8, 64);
      linv[j] = 1.f / rs;
    }
#pragma unroll
    for (int j = 0; j < 4; ++j)
#pragma unroll
      for (int jt = 0; jt < 7; ++jt) {
        bf16 bv = __float2bfloat16(p[jt][j] * linv[j]);
        pb[rband + j][jt * 16 + (lane & 15)] = *(short*)&bv;
      }
    __syncthreads();
    sh8 pa[4];
#pragma unroll
    for (int k2 = 0; k2 < 4; ++k2)
      pa[k2] = *(const sh8*)&pb[lane & 15][k2 * 32 + kq];
    f32x4 o[2] = {};
#pragma unroll
    for (int dt = 0; dt < 2; ++dt)
#pragma unroll
      for (int k2 = 0; k2 < 4; ++k2)
        o[dt] = __builtin_amdgcn_mfma_f32_16x16x32_bf16(pa[k2], vb[dt][k2], o[dt], 0, 0, 0);
#pragma unroll
    for (int j = 0; j < 4; ++j) {
      int r2 = it * 16 + rband + j;
      if (r2 < 98) {
#pragma unroll
        for (int dt = 0; dt < 2; ++dt) {
          bf16 ov = __float2bfloat16(o[dt][j]);
          aout[((size_t)wl * 98 + r2) * 256 + h * 32 + dt * 16 + (lane & 15)] = ov;
        }
      }
    }
    __syncthreads();
  }
}

// ---------------- residual + LN2: linear streaming ----------------
__global__ __launch_bounds__(256) void k_xres_ln2_lin(
    const float* __restrict__ xtw, const bf16* __restrict__ pout,
    const float* __restrict__ g, const float* __restrict__ bb,
    float* __restrict__ xres, bf16* __restrict__ ln2) {
  int rl = blockIdx.x * 4 + (threadIdx.x >> 6);
  int lane = threadIdx.x & 63;
  int c0 = lane * 4;
  float4 v = *(const float4*)(xtw + (size_t)rl * 256 + c0);
  ushort4 pu = *(const ushort4*)(pout + (size_t)rl * 256 + c0);
  v.x += __bfloat162float(*(bf16*)&pu.x);
  v.y += __bfloat162float(*(bf16*)&pu.y);
  v.z += __bfloat162float(*(bf16*)&pu.z);
  v.w += __bfloat162float(*(bf16*)&pu.w);
  *(float4*)(xres + (size_t)rl * 256 + c0) = v;
  float s = v.x + v.y + v.z + v.w;
  float s2 = v.x * v.x + v.y * v.y + v.z * v.z + v.w * v.w;
#pragma unroll
  for (int off = 32; off; off >>= 1) { s += __shfl_xor(s, off, 64); s2 += __shfl_xor(s2, off, 64); }
  float mu = s * (1.f / 256.f);
  float var = s2 * (1.f / 256.f) - mu * mu;
  float rs = rsqrtf(var + 1e-5f);
  float4 gg = *(const float4*)(g + c0);
  float4 bv = *(const float4*)(bb + c0);
  bf16 tmp[4];
  tmp[0] = __float2bfloat16((v.x - mu) * rs * gg.x + bv.x);
  tmp[1] = __float2bfloat16((v.y - mu) * rs * gg.y + bv.y);
  tmp[2] = __float2bfloat16((v.z - mu) * rs * gg.z + bv.z);
  tmp[3] = __float2bfloat16((v.w - mu) * rs * gg.w + bv.w);
  *(ushort4*)(&ln2[(size_t)rl * 256 + c0]) = *(ushort4*)tmp;
}

// ---------------- final: chunk-local y (f32 windowed) -> (B,D,C,W,H) ----------------
__global__ __launch_bounds__(256) void k_final_c(const float* __restrict__ y,
                                                 float* __restrict__ out, int cchunk) {
  int t = blockIdx.x;              // 672 = 84w * 4i * 2b
  int w0 = t % 84;
  int t2 = t / 84;
  int i = t2 & 3, b = t2 >> 2;
  int d0 = (cchunk * 4 + 1 + i) & 7;
  __shared__ float tile[84][65];
  __shared__ int rtab[84];
  int tid = threadIdx.x;
  if (tid < 84) rtab[tid] = inv_row(b, d0, w0, tid);
  __syncthreads();
  for (int c0 = 0; c0 < 256; c0 += 64) {
    for (int idx = tid; idx < 84 * 64; idx += 256) {
      int hh = idx >> 6, cc = idx & 63;
      tile[hh][cc] = y[(size_t)rtab[hh] * 256 + c0 + cc];
    }
    __syncthreads();
    for (int idx = tid; idx < 64 * 84; idx += 256) {
      int cc = idx / 84, hh = idx - cc * 84;
      out[((((size_t)b * 8 + d0) * 256 + c0 + cc) * 84 + w0) * 84 + hh] = tile[hh][cc];
    }
    __syncthreads();
  }
}

// ---------------- launch ----------------
extern "C" void kernel_launch(void* const* d_in, const int* in_sizes, int n_in,
                              void* d_out, int out_size, void* d_ws, size_t ws_size,
                              hipStream_t stream) {
  const float* x      = (const float*)d_in[0];
  const float* n1g    = (const float*)d_in[1];
  const float* n1b    = (const float*)d_in[2];
  const float* qkv_w  = (const float*)d_in[3];
  const float* rpb    = (const float*)d_in[4];
  const float* proj_w = (const float*)d_in[5];
  const float* proj_b = (const float*)d_in[6];
  const float* n2g    = (const float*)d_in[7];
  const float* n2b    = (const float*)d_in[8];
  const float* fc1_w  = (const float*)d_in[9];
  const float* fc1_b  = (const float*)d_in[10];
  const float* fc2_w  = (const float*)d_in[11];
  const float* fc2_b  = (const float*)d_in[12];
  float* out = (float*)d_out;

  // ---- persistent: weights + bias table ----
  char* w = (char*)d_ws;
  size_t off = 0;
  bf16* wq = (bf16*)(w + off); off += (size_t)768 * 256 * 2;
  bf16* wp = (bf16*)(w + off); off += (size_t)256 * 256 * 2;
  bf16* w1 = (bf16*)(w + off); off += (size_t)1024 * 256 * 2;
  bf16* w2 = (bf16*)(w + off); off += (size_t)1024 * 256 * 2;
  float* tbl = (float*)(w + off); off += (size_t)8 * 8 * 112 * 112 * 4;  // 3.2 MB

  // ---- per-chunk buffers ----
  float* xtw  = (float*)(w + off); off += (size_t)M2 * 1024;    // 57.8 MB (also y)
  bf16*  xw   = (bf16*)(w + off);  off += (size_t)M2 * 512;     // 28.9 MB (also aout)
  char*  qreg = w + off;           off += (size_t)M2 * 1536;    // 86.7 MB
  float* xres = (float*)(w + off); off += (size_t)M2 * 1024;    // 57.8 MB
  bf16*  hid  = (bf16*)(w + off);                               // tier-sized
  bf16* qkvb = (bf16*)qreg;
  bf16* aout = xw;
  bf16* pout = (bf16*)qreg;
  bf16* ln2b = (bf16*)(qreg + (size_t)M2 * 512);
  float* ybuf = xtw;

  // MLP tiers: full 441 (hid 115.6 MB; ws>=441MB measured via poison fill) / 147 / 49 / 21
  int subTiles = 21;
  if (off + (size_t)441 * 128 * 2048 + 1024 <= ws_size) subTiles = 441;
  else if (off + (size_t)147 * 128 * 2048 + 1024 <= ws_size) subTiles = 147;
  else if (off + (size_t)49 * 128 * 2048 + 1024 <= ws_size) subTiles = 49;
  const int nsub = 441 / subTiles;
  const int MSUB = subTiles * 128;

  // weights -> bf16, bias table
  k_f2b<<<(196608 + 255) / 256, 256, 0, stream>>>(qkv_w, wq, 196608);
  k_f2b<<<(65536 + 255) / 256, 256, 0, stream>>>(proj_w, wp, 65536);
  k_f2b<<<(262144 + 255) / 256, 256, 0, stream>>>(fc1_w, w1, 262144);
  k_f2b<<<(262144 + 255) / 256, 256, 0, stream>>>(fc2_w, w2, 262144);
  k_bias<<<64, 256, 0, stream>>>(rpb, tbl);

  for (int c = 0; c < 2; ++c) {
    k_xpose_w<<<1344, 256, 0, stream>>>(x, xtw, c);
    k_ln1_lin<<<M2 / 4, 256, 0, stream>>>(xtw, n1g, n1b, xw);
    k_gemm_bt<0><<<441 * 6, 256, 0, stream>>>(xw, wq, M2, 768, 256, nullptr, nullptr, qkvb);
    k_attn_mfma<<<NWC * NH, 64, 0, stream>>>(qkvb, tbl, aout, 2 * c);
    k_gemm_bt<0><<<441 * 2, 256, 0, stream>>>(aout, wp, M2, 256, 256, proj_b, nullptr, pout);
    k_xres_ln2_lin<<<M2 / 4, 256, 0, stream>>>(xtw, pout, n2g, n2b, xres, ln2b);
    for (int s = 0; s < nsub; ++s) {
      size_t m0 = (size_t)s * MSUB;
      k_gemm_bt<1><<<subTiles * 8, 256, 0, stream>>>(
          ln2b + m0 * 256, w1, MSUB, 1024, 256, fc1_b, nullptr, hid);
      k_gemm_bt<2><<<subTiles * 2, 256, 0, stream>>>(
          hid, w2, MSUB, 256, 1024, fc2_b, xres + m0 * 256, ybuf + m0 * 256);
    }
    k_final_c<<<672, 256, 0, stream>>>(ybuf, out, c);
  }
}

// Round 10
// 786.290 us; speedup vs baseline: 1.6143x; 1.0248x over previous
//
#include <hip/hip_runtime.h>
#include <hip/hip_bf16.h>
#include <cstdint>
#include <cstddef>

// ---- problem constants ----
#define B_   2
#define D_   8
#define C_   256
#define W_   84
#define H_   84
#define NH   8
#define HD   32
#define NTOK 98
#define WH   7056        // W_*H_
#define M2   56448       // rows per chunk = 576 windows * 98 (441 * 128)
#define NWC  576         // windows per chunk

typedef __attribute__((ext_vector_type(8))) short sh8;
typedef __attribute__((ext_vector_type(4))) float f32x4;
typedef __hip_bfloat16 bf16;

// ---------------- fp32 -> bf16 weight convert ----------------
__global__ __launch_bounds__(256) void k_f2b(const float* __restrict__ in,
                                             bf16* __restrict__ out, int n) {
  int i = blockIdx.x * 256 + threadIdx.x;
  if (i < n) out[i] = __float2bfloat16(in[i]);
}

// ---------------- bias+mask table: [8 cls][8 h][112][112] f32 ----------------
__global__ __launch_bounds__(256) void k_bias(const float* __restrict__ rpb,
                                              float* __restrict__ tbl) {
  int cls = blockIdx.x >> 3, h = blockIdx.x & 7;
  int dB = cls >> 2, hB = (cls >> 1) & 1, wB = cls & 1;
  for (int idx = threadIdx.x; idx < 112 * 112; idx += 256) {
    int r = idx / 112, c = idx - (idx / 112) * 112;
    int rt = r < 98 ? r : 97, ct = c < 98 ? c : 97;
    int jdr = rt / 49, remr = rt % 49, jhr = remr / 7, jwr = remr % 7;
    int jdc = ct / 49, remc = ct % 49, jhc = remc / 7, jwc = remc % 7;
    int bir = jdr * 169 + jhr * 13 + jwr, bic = jdc * 169 + jhc * 13 + jwc;
    int dgr = dB ? ((6 + jdr) < 7 ? 1 : 2) : 0;
    int hgr = hB ? ((77 + jhr) < 81 ? 1 : 2) : 0;
    int wgr = wB ? ((77 + jwr) < 81 ? 1 : 2) : 0;
    int dgc = dB ? ((6 + jdc) < 7 ? 1 : 2) : 0;
    int hgc = hB ? ((77 + jhc) < 81 ? 1 : 2) : 0;
    int wgc = wB ? ((77 + jwc) < 81 ? 1 : 2) : 0;
    int cir = dgr * 9 + hgr * 3 + wgr, cic = dgc * 9 + hgc * 3 + wgc;
    float v = rpb[(bir - bic + 253) * 8 + h] + (cir == cic ? 0.f : -100.f);
    tbl[((size_t)(cls * 8 + h) * 112 + r) * 112 + c] = v;
  }
}

// inverse map: src/dst plane (b,d0,w0,h0) -> chunk-local row
__device__ __forceinline__ int inv_row(int b, int d0, int w0, int h0) {
  int sd = (d0 + 7) & 7;
  int lid = (sd >> 1) & 1, jd = sd & 1;
  int sh = h0 + 81; if (sh >= 84) sh -= 84;
  int sw = w0 + 81; if (sw >= 84) sw -= 84;
  int ih = sh / 7, jh = sh - ih * 7;
  int iw = sw / 7, jw = sw - iw * 7;
  return (b * 288 + lid * 144 + ih * 12 + iw) * 98 + jd * 49 + jh * 7 + jw;
}

// ---------------- x (B,D,C,W,H) -> xtw windowed rows x 256, f32 ----------------
__global__ __launch_bounds__(256) void k_xpose_w(const float* __restrict__ x,
                                                 float* __restrict__ xtw, int cchunk) {
  int blk = blockIdx.x;            // 1344 = 2ch * 84w * 4i * 2b
  int ch = blk & 1;
  int t = blk >> 1;
  int w0 = t % 84;
  int t2 = t / 84;
  int i = t2 & 3, b = t2 >> 2;
  int d0 = (cchunk * 4 + 1 + i) & 7;
  __shared__ float tile[128][85];
  __shared__ int rtab[84];
  int tid = threadIdx.x;
  if (tid < 84) rtab[tid] = inv_row(b, d0, w0, tid);
  const float* src = x + ((size_t)(b * 8 + d0) * 256 + ch * 128) * WH + w0 * 84;
  for (int idx = tid; idx < 128 * 21; idx += 256) {
    int c = idx / 21, h4 = idx - c * 21;
    float4 v = *(const float4*)(src + (size_t)c * WH + h4 * 4);
    tile[c][h4 * 4 + 0] = v.x; tile[c][h4 * 4 + 1] = v.y;
    tile[c][h4 * 4 + 2] = v.z; tile[c][h4 * 4 + 3] = v.w;
  }
  __syncthreads();
  for (int idx = tid; idx < 84 * 128; idx += 256) {
    int h = idx >> 7, cc = idx & 127;
    xtw[(size_t)rtab[h] * 256 + ch * 128 + cc] = tile[cc][h];
  }
}

// ---------------- LN1: linear streaming ----------------
__global__ __launch_bounds__(256) void k_ln1_lin(
    const float* __restrict__ xtw, const float* __restrict__ g,
    const float* __restrict__ bb, bf16* __restrict__ xw) {
  int rl = blockIdx.x * 4 + (threadIdx.x >> 6);
  int lane = threadIdx.x & 63;
  int c0 = lane * 4;
  float4 v = *(const float4*)(xtw + (size_t)rl * 256 + c0);
  float s = v.x + v.y + v.z + v.w;
  float s2 = v.x * v.x + v.y * v.y + v.z * v.z + v.w * v.w;
#pragma unroll
  for (int off = 32; off; off >>= 1) { s += __shfl_xor(s, off, 64); s2 += __shfl_xor(s2, off, 64); }
  float mu = s * (1.f / 256.f);
  float var = s2 * (1.f / 256.f) - mu * mu;
  float rs = rsqrtf(var + 1e-5f);
  float4 gg = *(const float4*)(g + c0);
  float4 bv = *(const float4*)(bb + c0);
  bf16 tmp[4];
  tmp[0] = __float2bfloat16((v.x - mu) * rs * gg.x + bv.x);
  tmp[1] = __float2bfloat16((v.y - mu) * rs * gg.y + bv.y);
  tmp[2] = __float2bfloat16((v.z - mu) * rs * gg.z + bv.z);
  tmp[3] = __float2bfloat16((v.w - mu) * rs * gg.w + bv.w);
  *(ushort4*)(&xw[(size_t)rl * 256 + c0]) = *(ushort4*)tmp;
}

// fast exact-GELU: erf via Abramowitz-Stegun 7.1.26 (|err| ~ 3e-7)
__device__ __forceinline__ float gelu_fast(float v) {
  float x = v * 0.70710678118f;
  float ax = fabsf(x);
  float t = 1.0f / (1.0f + 0.3275911f * ax);
  float y = t * (0.254829592f + t * (-0.284496736f +
            t * (1.421413741f + t * (-1.453152027f + t * 1.061405429f))));
  float er = 1.0f - y * __expf(-ax * ax);
  er = copysignf(er, x);
  return 0.5f * v * (1.0f + er);
}

// ---------------- bf16 B^T GEMM: BK=32, 3-buffer counted-vmcnt pipeline ----------------
// LDS rows are 64B (16 banks) -> bank-group = (row&1, chunk). Swizzle chunk ^= (row>>1)&3
// makes every 8-consecutive-lane phase cover all 8 groups (phase-complete -> conflict-free).
// Source pre-swizzle: cSrc chunk = (l&3)^((l>>3)&3); read: kswz chunk = (l>>4)^((l>>1)&3).
// Pipeline: B1 barrier (reuse-buffer readers done) -> stage(kt+2) -> vmcnt(8) (kt's loads
// retired, 8 newer in flight; T4: never drain to 0 in-loop) -> B2 barrier -> ds_read+MFMA.
// EPI 0: (+bias) -> bf16   EPI 1: +bias, GELU -> bf16   EPI 2: +bias +res -> f32 linear
template <int EPI>
__global__ __launch_bounds__(256) void k_gemm_bt(
    const bf16* __restrict__ A, const bf16* __restrict__ Bw,
    int M, int N, int K,
    const float* __restrict__ bias, const float* __restrict__ res,
    void* __restrict__ outv) {
  __shared__ __align__(16) short smem[24576];   // 48 KB: 3 bufs x (sA 4096 | sB 4096 shorts)
  // ---- bijective XCD swizzle ----
  int nwg = gridDim.x;
  int orig = blockIdx.x;
  int q8 = nwg >> 3, r8 = nwg & 7;
  int xcd = orig & 7, lwg = orig >> 3;
  int bid = (xcd < r8 ? xcd * (q8 + 1) : r8 * (q8 + 1) + (xcd - r8) * q8) + lwg;
  int nbn = N >> 7;
  int bm = bid / nbn, bn = bid - bm * nbn;
  int tid = threadIdx.x;
  int lane = tid & 63, wv = tid >> 6;
  int wr = wv >> 1, wc = wv & 1;
  f32x4 acc[4][4] = {};
  const short* Ag = (const short*)A + (size_t)bm * 128 * K;
  const short* Bg = (const short*)Bw + (size_t)bn * 128 * K;
  // staging: lane l -> row group + (l>>2), dest chunk l&3; source chunk = (l&3)^((l>>3)&3)
  int rIn = lane >> 2;
  int cSrc = ((lane & 3) ^ ((lane >> 3) & 3)) * 8;   // shorts
  int nk = K >> 5;

  auto stage = [&](int buf, int kt) {
    short* sA = smem + buf * 8192;
    short* sB = sA + 4096;
#pragma unroll
    for (int rr = 0; rr < 2; ++rr) {
      int r0 = wv * 32 + rr * 16;
      const short* ga = Ag + (size_t)(r0 + rIn) * K + kt * 32 + cSrc;
      const short* gb = Bg + (size_t)(r0 + rIn) * K + kt * 32 + cSrc;
      __builtin_amdgcn_global_load_lds(
          (const __attribute__((address_space(1))) void*)ga,
          (__attribute__((address_space(3))) void*)&sA[r0 * 32], 16, 0, 0);
      __builtin_amdgcn_global_load_lds(
          (const __attribute__((address_space(1))) void*)gb,
          (__attribute__((address_space(3))) void*)&sB[r0 * 32], 16, 0, 0);
    }
  };

  stage(0, 0);
  stage(1, 1);
  int rdBuf = 0, wrBuf = 2;
  int rb = wr * 64 + (lane & 15);
  int cb = wc * 64 + (lane & 15);
  int kswz = (((lane >> 4) ^ ((lane >> 1) & 3))) * 8;  // phase-complete swizzled chunk
  for (int kt = 0; kt < nk; ++kt) {
    __builtin_amdgcn_s_barrier();            // B1: all readers of wrBuf (iter kt-1) done
    if (kt + 2 < nk) {
      stage(wrBuf, kt + 2);
      asm volatile("s_waitcnt vmcnt(8)" ::: "memory");   // kt's 4 loads retired
    } else if (kt + 1 < nk) {
      asm volatile("s_waitcnt vmcnt(4)" ::: "memory");
    } else {
      asm volatile("s_waitcnt vmcnt(0)" ::: "memory");
    }
    __builtin_amdgcn_s_barrier();            // B2: kt's tile visible to all waves
    __builtin_amdgcn_sched_barrier(0);
    const short* sA = smem + rdBuf * 8192;
    const short* sB = sA + 4096;
    sh8 af[4], bfr[4];
#pragma unroll
    for (int m = 0; m < 4; ++m) af[m] = *(const sh8*)&sA[(rb + m * 16) * 32 + kswz];
#pragma unroll
    for (int n2 = 0; n2 < 4; ++n2) bfr[n2] = *(const sh8*)&sB[(cb + n2 * 16) * 32 + kswz];
#pragma unroll
    for (int m = 0; m < 4; ++m)
#pragma unroll
      for (int n2 = 0; n2 < 4; ++n2)
        acc[m][n2] = __builtin_amdgcn_mfma_f32_16x16x32_bf16(af[m], bfr[n2], acc[m][n2], 0, 0, 0);
    rdBuf = (rdBuf + 1 == 3) ? 0 : rdBuf + 1;
    wrBuf = (wrBuf + 1 == 3) ? 0 : wrBuf + 1;
  }
  // direct epilogue
  int rbase = bm * 128 + wr * 64 + ((lane >> 4) << 2);
  int cbase = bn * 128 + wc * 64 + (lane & 15);
#pragma unroll
  for (int m = 0; m < 4; ++m) {
#pragma unroll
    for (int j = 0; j < 4; ++j) {
      int r = rbase + m * 16 + j;
#pragma unroll
      for (int n2 = 0; n2 < 4; ++n2) {
        int cc = cbase + n2 * 16;
        float v = acc[m][n2][j];
        if (EPI == 2) {
          v += bias[cc] + res[(size_t)r * N + cc];
          ((float*)outv)[(size_t)r * N + cc] = v;
        } else {
          if (bias) v += bias[cc];
          if (EPI == 1) v = gelu_fast(v);
          ((bf16*)outv)[(size_t)r * N + cc] = __float2bfloat16(v);
        }
      }
    }
  }
}

// ---------------- MFMA windowed attention: 1 wave per (window, head) ----------------
__global__ __launch_bounds__(64) void k_attn_mfma(
    const bf16* __restrict__ qkv, const float* __restrict__ tbl,
    bf16* __restrict__ aout, int idbase) {
  int blk = blockIdx.x;
  int wl = blk >> 3, h = blk & 7;
  int lid = (wl / 144) & 1;
  int id = idbase + lid;
  int rem = wl % 144;
  int ih = rem / 12, iw = rem - ih * 12;
  int cls = ((id == 3) ? 4 : 0) + ((ih == 11) ? 2 : 0) + ((iw == 11) ? 1 : 0);
  const float* bt = tbl + (size_t)(cls * 8 + h) * 112 * 112;
  int lane = threadIdx.x;
  __shared__ __align__(16) short vt[32][136];   // V^T, padded
  __shared__ __align__(16) short pb[16][136];   // P band
  sh8 z = {};
  for (int i = lane; i < 544; i += 64) *((sh8*)&vt[0][0] + i) = z;
  for (int i = lane; i < 272; i += 64) *((sh8*)&pb[0][0] + i) = z;
  __syncthreads();
  const size_t base = (size_t)wl * NTOK * 768;
  for (int i = lane; i < 98 * 8; i += 64) {
    int c = i >> 3, d4 = (i & 7) * 4;
    ushort4 vu = *(const ushort4*)&qkv[base + (size_t)c * 768 + 512 + h * 32 + d4];
    vt[d4 + 0][c] = (short)vu.x; vt[d4 + 1][c] = (short)vu.y;
    vt[d4 + 2][c] = (short)vu.z; vt[d4 + 3][c] = (short)vu.w;
  }
  int kq = (lane >> 4) * 8;
  sh8 kf[7];
#pragma unroll
  for (int jt = 0; jt < 7; ++jt) {
    int c = jt * 16 + (lane & 15);
    kf[jt] = *(const sh8*)&qkv[base + (size_t)c * 768 + 256 + h * 32 + kq];
  }
  __syncthreads();
  sh8 vb[2][4];
#pragma unroll
  for (int dt = 0; dt < 2; ++dt)
#pragma unroll
    for (int k2 = 0; k2 < 4; ++k2)
      vb[dt][k2] = *(const sh8*)&vt[dt * 16 + (lane & 15)][k2 * 32 + kq];

  const float scale = 0.17677669529663687f;
  f32x4 zc = {};
  int rband = (lane >> 4) * 4;
  for (int it = 0; it < 7; ++it) {
    int rq = it * 16 + (lane & 15);
    sh8 qf = *(const sh8*)&qkv[base + (size_t)rq * 768 + h * 32 + kq];
    f32x4 s[7];
#pragma unroll
    for (int jt = 0; jt < 7; ++jt)
      s[jt] = __builtin_amdgcn_mfma_f32_16x16x32_bf16(qf, kf[jt], zc, 0, 0, 0);
    float p[7][4], linv[4];
#pragma unroll
    for (int j = 0; j < 4; ++j) {
      int r2 = it * 16 + rband + j;
      float rs = 0.f;
#pragma unroll
      for (int jt = 0; jt < 7; ++jt) {
        int c = jt * 16 + (lane & 15);
        float v = s[jt][j] * scale + bt[r2 * 112 + c];
        float e = __expf(v);
        if (jt == 6 && (lane & 15) >= 2) e = 0.f;
        p[jt][j] = e;
        rs += e;
      }
      rs += __shfl_xor(rs, 1, 64); rs += __shfl_xor(rs, 2, 64);
      rs += __shfl_xor(rs, 4, 64); rs += __shfl_xor(rs, 8, 64);
      linv[j] = 1.f / rs;
    }
#pragma unroll
    for (int j = 0; j < 4; ++j)
#pragma unroll
      for (int jt = 0; jt < 7; ++jt) {
        bf16 bv = __float2bfloat16(p[jt][j] * linv[j]);
        pb[rband + j][jt * 16 + (lane & 15)] = *(short*)&bv;
      }
    __syncthreads();
    sh8 pa[4];
#pragma unroll
    for (int k2 = 0; k2 < 4; ++k2)
      pa[k2] = *(const sh8*)&pb[lane & 15][k2 * 32 + kq];
    f32x4 o[2] = {};
#pragma unroll
    for (int dt = 0; dt < 2; ++dt)
#pragma unroll
      for (int k2 = 0; k2 < 4; ++k2)
        o[dt] = __builtin_amdgcn_mfma_f32_16x16x32_bf16(pa[k2], vb[dt][k2], o[dt], 0, 0, 0);
#pragma unroll
    for (int j = 0; j < 4; ++j) {
      int r2 = it * 16 + rband + j;
      if (r2 < 98) {
#pragma unroll
        for (int dt = 0; dt < 2; ++dt) {
          bf16 ov = __float2bfloat16(o[dt][j]);
          aout[((size_t)wl * 98 + r2) * 256 + h * 32 + dt * 16 + (lane & 15)] = ov;
        }
      }
    }
    __syncthreads();
  }
}

// ---------------- residual + LN2: linear streaming ----------------
__global__ __launch_bounds__(256) void k_xres_ln2_lin(
    const float* __restrict__ xtw, const bf16* __restrict__ pout,
    const float* __restrict__ g, const float* __restrict__ bb,
    float* __restrict__ xres, bf16* __restrict__ ln2) {
  int rl = blockIdx.x * 4 + (threadIdx.x >> 6);
  int lane = threadIdx.x & 63;
  int c0 = lane * 4;
  float4 v = *(const float4*)(xtw + (size_t)rl * 256 + c0);
  ushort4 pu = *(const ushort4*)(pout + (size_t)rl * 256 + c0);
  v.x += __bfloat162float(*(bf16*)&pu.x);
  v.y += __bfloat162float(*(bf16*)&pu.y);
  v.z += __bfloat162float(*(bf16*)&pu.z);
  v.w += __bfloat162float(*(bf16*)&pu.w);
  *(float4*)(xres + (size_t)rl * 256 + c0) = v;
  float s = v.x + v.y + v.z + v.w;
  float s2 = v.x * v.x + v.y * v.y + v.z * v.z + v.w * v.w;
#pragma unroll
  for (int off = 32; off; off >>= 1) { s += __shfl_xor(s, off, 64); s2 += __shfl_xor(s2, off, 64); }
  float mu = s * (1.f / 256.f);
  float var = s2 * (1.f / 256.f) - mu * mu;
  float rs = rsqrtf(var + 1e-5f);
  float4 gg = *(const float4*)(g + c0);
  float4 bv = *(const float4*)(bb + c0);
  bf16 tmp[4];
  tmp[0] = __float2bfloat16((v.x - mu) * rs * gg.x + bv.x);
  tmp[1] = __float2bfloat16((v.y - mu) * rs * gg.y + bv.y);
  tmp[2] = __float2bfloat16((v.z - mu) * rs * gg.z + bv.z);
  tmp[3] = __float2bfloat16((v.w - mu) * rs * gg.w + bv.w);
  *(ushort4*)(&ln2[(size_t)rl * 256 + c0]) = *(ushort4*)tmp;
}

// ---------------- final: chunk-local y (f32 windowed) -> (B,D,C,W,H) ----------------
__global__ __launch_bounds__(256) void k_final_c(const float* __restrict__ y,
                                                 float* __restrict__ out, int cchunk) {
  int t = blockIdx.x;              // 672 = 84w * 4i * 2b
  int w0 = t % 84;
  int t2 = t / 84;
  int i = t2 & 3, b = t2 >> 2;
  int d0 = (cchunk * 4 + 1 + i) & 7;
  __shared__ float tile[84][65];
  __shared__ int rtab[84];
  int tid = threadIdx.x;
  if (tid < 84) rtab[tid] = inv_row(b, d0, w0, tid);
  __syncthreads();
  for (int c0 = 0; c0 < 256; c0 += 64) {
    for (int idx = tid; idx < 84 * 64; idx += 256) {
      int hh = idx >> 6, cc = idx & 63;
      tile[hh][cc] = y[(size_t)rtab[hh] * 256 + c0 + cc];
    }
    __syncthreads();
    for (int idx = tid; idx < 64 * 84; idx += 256) {
      int cc = idx / 84, hh = idx - cc * 84;
      out[((((size_t)b * 8 + d0) * 256 + c0 + cc) * 84 + w0) * 84 + hh] = tile[hh][cc];
    }
    __syncthreads();
  }
}

// ---------------- launch ----------------
extern "C" void kernel_launch(void* const* d_in, const int* in_sizes, int n_in,
                              void* d_out, int out_size, void* d_ws, size_t ws_size,
                              hipStream_t stream) {
  const float* x      = (const float*)d_in[0];
  const float* n1g    = (const float*)d_in[1];
  const float* n1b    = (const float*)d_in[2];
  const float* qkv_w  = (const float*)d_in[3];
  const float* rpb    = (const float*)d_in[4];
  const float* proj_w = (const float*)d_in[5];
  const float* proj_b = (const float*)d_in[6];
  const float* n2g    = (const float*)d_in[7];
  const float* n2b    = (const float*)d_in[8];
  const float* fc1_w  = (const float*)d_in[9];
  const float* fc1_b  = (const float*)d_in[10];
  const float* fc2_w  = (const float*)d_in[11];
  const float* fc2_b  = (const float*)d_in[12];
  float* out = (float*)d_out;

  // ---- persistent: weights + bias table ----
  char* w = (char*)d_ws;
  size_t off = 0;
  bf16* wq = (bf16*)(w + off); off += (size_t)768 * 256 * 2;
  bf16* wp = (bf16*)(w + off); off += (size_t)256 * 256 * 2;
  bf16* w1 = (bf16*)(w + off); off += (size_t)1024 * 256 * 2;
  bf16* w2 = (bf16*)(w + off); off += (size_t)1024 * 256 * 2;
  float* tbl = (float*)(w + off); off += (size_t)8 * 8 * 112 * 112 * 4;  // 3.2 MB

  // ---- per-chunk buffers ----
  float* xtw  = (float*)(w + off); off += (size_t)M2 * 1024;    // 57.8 MB (also y)
  bf16*  xw   = (bf16*)(w + off);  off += (size_t)M2 * 512;     // 28.9 MB (also aout)
  char*  qreg = w + off;           off += (size_t)M2 * 1536;    // 86.7 MB
  float* xres = (float*)(w + off); off += (size_t)M2 * 1024;    // 57.8 MB
  bf16*  hid  = (bf16*)(w + off);                               // tier-sized
  bf16* qkvb = (bf16*)qreg;
  bf16* aout = xw;
  bf16* pout = (bf16*)qreg;
  bf16* ln2b = (bf16*)(qreg + (size_t)M2 * 512);
  float* ybuf = xtw;

  // MLP tiers: full 441 (hid 115.6 MB; ws>=441MB measured via poison fill) / 147 / 49 / 21
  int subTiles = 21;
  if (off + (size_t)441 * 128 * 2048 + 1024 <= ws_size) subTiles = 441;
  else if (off + (size_t)147 * 128 * 2048 + 1024 <= ws_size) subTiles = 147;
  else if (off + (size_t)49 * 128 * 2048 + 1024 <= ws_size) subTiles = 49;
  const int nsub = 441 / subTiles;
  const int MSUB = subTiles * 128;

  // weights -> bf16, bias table
  k_f2b<<<(196608 + 255) / 256, 256, 0, stream>>>(qkv_w, wq, 196608);
  k_f2b<<<(65536 + 255) / 256, 256, 0, stream>>>(proj_w, wp, 65536);
  k_f2b<<<(262144 + 255) / 256, 256, 0, stream>>>(fc1_w, w1, 262144);
  k_f2b<<<(262144 + 255) / 256, 256, 0, stream>>>(fc2_w, w2, 262144);
  k_bias<<<64, 256, 0, stream>>>(rpb, tbl);

  for (int c = 0; c < 2; ++c) {
    k_xpose_w<<<1344, 256, 0, stream>>>(x, xtw, c);
    k_ln1_lin<<<M2 / 4, 256, 0, stream>>>(xtw, n1g, n1b, xw);
    k_gemm_bt<0><<<441 * 6, 256, 0, stream>>>(xw, wq, M2, 768, 256, nullptr, nullptr, qkvb);
    k_attn_mfma<<<NWC * NH, 64, 0, stream>>>(qkvb, tbl, aout, 2 * c);
    k_gemm_bt<0><<<441 * 2, 256, 0, stream>>>(aout, wp, M2, 256, 256, proj_b, nullptr, pout);
    k_xres_ln2_lin<<<M2 / 4, 256, 0, stream>>>(xtw, pout, n2g, n2b, xres, ln2b);
    for (int s = 0; s < nsub; ++s) {
      size_t m0 = (size_t)s * MSUB;
      k_gemm_bt<1><<<subTiles * 8, 256, 0, stream>>>(
          ln2b + m0 * 256, w1, MSUB, 1024, 256, fc1_b, nullptr, hid);
      k_gemm_bt<2><<<subTiles * 2, 256, 0, stream>>>(
          hid, w2, MSUB, 256, 1024, fc2_b, xres + m0 * 256, ybuf + m0 * 256);
    }
    k_final_c<<<672, 256, 0, stream>>>(ybuf, out, c);
  }
}